// Round 2
// baseline (2719.170 us; speedup 1.0000x reference)
//
#include <hip/hip_runtime.h>
#include <hip/hip_bf16.h>
#include <math.h>

// Swin block, MI355X round 1: low-workspace (156MB) correctness build.
// fp32 VALU GEMMs, bf16 intermediates. M=200704, C=96, heads=3, hd=32, WS=7.

__device__ __forceinline__ float bf2f(unsigned short u){
  union { unsigned int i; float f; } c; c.i = ((unsigned int)u) << 16; return c.f;
}
__device__ __forceinline__ unsigned short f2bf(float f){
  __hip_bfloat16 h = __float2bfloat16(f);
  union { __hip_bfloat16 h; unsigned short u; } c; c.h = h; return c.u;
}

// window-order row r (win*49+n) -> image row (b*12544 + h*112 + w), shift +3.
__device__ __forceinline__ int win_to_img(int r){
  int win = r / 49, n = r - win * 49;
  int b  = win >> 8, wi = win & 255;
  int wh = wi >> 4,  ww = wi & 15;
  int i  = n / 7,    j  = n - i * 7;
  int hs = wh * 7 + i + 3; if (hs >= 112) hs -= 112;
  int ws = ww * 7 + j + 3; if (ws >= 112) ws -= 112;
  return b * 12544 + hs * 112 + ws;
}

// ---- LN1 row stats over x (token order) -------------------------------------
__global__ __launch_bounds__(256) void ln_stats_kernel(
    const float* __restrict__ x, float* __restrict__ mean_out, float* __restrict__ rstd_out)
{
  int lane = threadIdx.x & 63;
  int r = (blockIdx.x << 2) + (threadIdx.x >> 6);
  const float* row = x + (size_t)r * 96;
  float v0 = row[lane];
  float v1 = (lane < 32) ? row[64 + lane] : 0.f;
  float s = v0 + v1, q = v0 * v0 + v1 * v1;
  #pragma unroll
  for (int off = 32; off; off >>= 1){ s += __shfl_xor(s, off); q += __shfl_xor(q, off); }
  float mean = s * (1.f / 96.f);
  float var  = q * (1.f / 96.f) - mean * mean;
  if (lane == 0){ mean_out[r] = mean; rstd_out[r] = rsqrtf(var + 1e-5f); }
}

// ---- attention: one block per window, 3 heads; writes output into q-slots ---
__global__ __launch_bounds__(256) void attn_kernel(
    unsigned short* __restrict__ qkv, const float* __restrict__ mask,
    const float* __restrict__ relt)
{
  __shared__ float          qs[49 * 97];       // scaled q, fp32
  __shared__ unsigned short ks[49 * 100];      // bf16
  __shared__ unsigned short vs[49 * 100];      // bf16
  __shared__ float          S[147 * 50];
  int win = blockIdx.x;
  int tid = threadIdx.x;
  const float scale = 0.17677669529663687f;    // 32^-0.5
  size_t base = (size_t)win * 49 * 288;
  for (int idx = tid; idx < 49 * 288; idx += 256){
    int n = idx / 288, c = idx - n * 288;
    unsigned short val = qkv[base + (size_t)n * 288 + c];
    int sect = c / 96, cc = c - sect * 96;
    if (sect == 0)      qs[n * 97  + cc] = bf2f(val) * scale;
    else if (sect == 1) ks[n * 100 + cc] = val;
    else                vs[n * 100 + cc] = val;
  }
  __syncthreads();
  int t = tid;
  if (t < 147){
    int hh = t / 49, p = t - hh * 49;
    float qr[32];
    #pragma unroll
    for (int d = 0; d < 32; d++) qr[d] = qs[p * 97 + hh * 32 + d];
    int i1 = p / 7, j1 = p - i1 * 7;
    const float* mrow = mask + (size_t)(win & 255) * 2401 + p * 49;
    float* Srow = S + t * 50;
    for (int m = 0; m < 49; m++){
      float dot = 0.f;
      #pragma unroll
      for (int d = 0; d < 32; d++) dot += qr[d] * bf2f(ks[m * 100 + hh * 32 + d]);
      int i2 = m / 7, j2 = m - i2 * 7;
      int ridx = (i1 - i2 + 6) * 13 + (j1 - j2 + 6);
      Srow[m] = dot + relt[ridx * 3 + hh] + mrow[m];
    }
    float mx = -1e30f;
    for (int m = 0; m < 49; m++) mx = fmaxf(mx, Srow[m]);
    float sum = 0.f;
    for (int m = 0; m < 49; m++){ float e = __expf(Srow[m] - mx); Srow[m] = e; sum += e; }
    float inv = 1.f / sum;
    float acc[32];
    #pragma unroll
    for (int d = 0; d < 32; d++) acc[d] = 0.f;
    for (int m = 0; m < 49; m++){
      float pm = Srow[m];
      #pragma unroll
      for (int d = 0; d < 32; d++) acc[d] += pm * bf2f(vs[m * 100 + hh * 32 + d]);
    }
    // in-place: overwrite this window's q-slot (only this block reads it)
    unsigned short* orow = qkv + base + (size_t)p * 288 + hh * 32;
    #pragma unroll
    for (int d = 0; d < 32; d++) orow[d] = f2bf(acc[d] * inv);
  }
}

// ---- generic tiled GEMM: out = A @ W^T + bias (+epilogue) -------------------
// AMODE: 0 = bf16 A (row stride ASTRIDE), 3 = fp32 A gathered via win_to_img
//        with fused LN (stats in mean/rstd, params lng/lnb)
// OMODE: 0 = bf16 out (row stride N), 2 = bf16 out + resid, scatter win_to_img
template<int K, int N, int AMODE, int OMODE, int ASTRIDE>
__global__ __launch_bounds__(256) void gemm_kernel(
    const void* __restrict__ Ap, const float* __restrict__ W, const float* __restrict__ bias,
    const float* __restrict__ mean, const float* __restrict__ rstd,
    const float* __restrict__ lng, const float* __restrict__ lnb,
    const float* __restrict__ resid, void* __restrict__ outp)
{
  __shared__ float As[64 * 17];
  __shared__ float Wsm[96 * 17];
  int tid = threadIdx.x;
  int tx = tid & 15, ty = tid >> 4;
  int row0 = blockIdx.y * 64;
  int col0 = blockIdx.x * 96;

  float acc[4][6];
  #pragma unroll
  for (int i = 0; i < 4; i++)
    #pragma unroll
    for (int j = 0; j < 6; j++) acc[i][j] = 0.f;

  int ar = tid >> 2;
  int ak = (tid & 3) * 4;
  float lm = 0.f, lr = 0.f;
  int gr = 0;
  if (AMODE == 3){ gr = win_to_img(row0 + ar); lm = mean[gr]; lr = rstd[gr]; }

  for (int k0 = 0; k0 < K; k0 += 16){
    if (AMODE == 0){
      const unsigned short* Abf = (const unsigned short*)Ap;
      ushort4 u = *reinterpret_cast<const ushort4*>(Abf + (size_t)(row0 + ar) * ASTRIDE + k0 + ak);
      As[ar * 17 + ak + 0] = bf2f(u.x);
      As[ar * 17 + ak + 1] = bf2f(u.y);
      As[ar * 17 + ak + 2] = bf2f(u.z);
      As[ar * 17 + ak + 3] = bf2f(u.w);
    } else {
      const float* Af = (const float*)Ap;
      float4 f = *reinterpret_cast<const float4*>(Af + (size_t)gr * 96 + k0 + ak);
      As[ar * 17 + ak + 0] = (f.x - lm) * lr * lng[k0 + ak + 0] + lnb[k0 + ak + 0];
      As[ar * 17 + ak + 1] = (f.y - lm) * lr * lng[k0 + ak + 1] + lnb[k0 + ak + 1];
      As[ar * 17 + ak + 2] = (f.z - lm) * lr * lng[k0 + ak + 2] + lnb[k0 + ak + 2];
      As[ar * 17 + ak + 3] = (f.w - lm) * lr * lng[k0 + ak + 3] + lnb[k0 + ak + 3];
    }
    #pragma unroll
    for (int t = 0; t < 6; t++){
      int idx = tid + 256 * t;
      int c = idx >> 4, kk = idx & 15;
      Wsm[c * 17 + kk] = W[(size_t)(col0 + c) * K + k0 + kk];
    }
    __syncthreads();
    #pragma unroll
    for (int kk = 0; kk < 16; kk++){
      float a[4], w[6];
      #pragma unroll
      for (int i = 0; i < 4; i++) a[i] = As[(ty * 4 + i) * 17 + kk];
      #pragma unroll
      for (int j = 0; j < 6; j++) w[j] = Wsm[(tx + 16 * j) * 17 + kk];
      #pragma unroll
      for (int i = 0; i < 4; i++)
        #pragma unroll
        for (int j = 0; j < 6; j++) acc[i][j] += a[i] * w[j];
    }
    __syncthreads();
  }

  #pragma unroll
  for (int i = 0; i < 4; i++){
    int r = row0 + ty * 4 + i;
    int orow = (OMODE == 2) ? win_to_img(r) : r;
    #pragma unroll
    for (int j = 0; j < 6; j++){
      int c = col0 + tx + 16 * j;
      float v = acc[i][j] + bias[c];
      if (OMODE == 0){
        ((unsigned short*)outp)[(size_t)r * N + c] = f2bf(v);
      } else {
        ((unsigned short*)outp)[(size_t)orow * 96 + c] =
            f2bf(v + resid[(size_t)orow * 96 + c]);
      }
    }
  }
}

// ---- fused MLP: LN2 + fc1 + GELU + fc2 + residual ---------------------------
__global__ __launch_bounds__(256) void fused_mlp_kernel(
    const unsigned short* __restrict__ x2, const float* __restrict__ g,
    const float* __restrict__ b, const float* __restrict__ fc1_w,
    const float* __restrict__ fc1_b, const float* __restrict__ fc2_w,
    const float* __restrict__ fc2_b, float* __restrict__ out)
{
  __shared__ float          As[64 * 97];       // LN2(x2) tile
  __shared__ unsigned short Wsm[96 * 97];      // weight chunk, bf16
  __shared__ float          Hs[64 * 97];       // hidden chunk
  int tid = threadIdx.x;
  int tx = tid & 15, ty = tid >> 4;
  int row0 = blockIdx.x * 64;

  // stage x2 tile (bf16 -> fp32)
  #pragma unroll
  for (int t = 0; t < 6; t++){
    int idx = t * 256 + tid;
    int r = idx / 24, c4 = idx - r * 24;
    ushort4 u = *reinterpret_cast<const ushort4*>(x2 + (size_t)(row0 + r) * 96 + c4 * 4);
    As[r * 97 + c4 * 4 + 0] = bf2f(u.x);
    As[r * 97 + c4 * 4 + 1] = bf2f(u.y);
    As[r * 97 + c4 * 4 + 2] = bf2f(u.z);
    As[r * 97 + c4 * 4 + 3] = bf2f(u.w);
  }
  __syncthreads();

  // LN2: 4 threads per row
  {
    int rr = tid >> 2, part = tid & 3;
    float s = 0.f, q = 0.f;
    #pragma unroll
    for (int c = 0; c < 24; c++){
      float v = As[rr * 97 + part * 24 + c];
      s += v; q += v * v;
    }
    s += __shfl_xor(s, 1); q += __shfl_xor(q, 1);
    s += __shfl_xor(s, 2); q += __shfl_xor(q, 2);
    float mean = s * (1.f / 96.f);
    float var  = q * (1.f / 96.f) - mean * mean;
    float rs = rsqrtf(var + 1e-5f);
    #pragma unroll
    for (int c = 0; c < 24; c++){
      int cc = part * 24 + c;
      float v = As[rr * 97 + cc];
      As[rr * 97 + cc] = (v - mean) * rs * g[cc] + b[cc];
    }
  }
  __syncthreads();

  float acc2[4][6];
  #pragma unroll
  for (int i = 0; i < 4; i++)
    #pragma unroll
    for (int j = 0; j < 6; j++) acc2[i][j] = 0.f;

  for (int chunk = 0; chunk < 4; chunk++){
    int c0 = chunk * 96;
    // stage fc1_w chunk (rows c0..c0+95, 96 k) as bf16
    #pragma unroll
    for (int t = 0; t < 9; t++){
      int idx = t * 256 + tid;
      int r = idx / 24, c4 = idx - r * 24;
      float4 f = *reinterpret_cast<const float4*>(fc1_w + (size_t)(c0 + r) * 96 + c4 * 4);
      Wsm[r * 97 + c4 * 4 + 0] = f2bf(f.x);
      Wsm[r * 97 + c4 * 4 + 1] = f2bf(f.y);
      Wsm[r * 97 + c4 * 4 + 2] = f2bf(f.z);
      Wsm[r * 97 + c4 * 4 + 3] = f2bf(f.w);
    }
    __syncthreads();
    // fc1 microkernel + GELU -> Hs
    {
      float acc1[4][6];
      #pragma unroll
      for (int i = 0; i < 4; i++)
        #pragma unroll
        for (int j = 0; j < 6; j++) acc1[i][j] = 0.f;
      for (int kk = 0; kk < 96; kk++){
        float a[4], w[6];
        #pragma unroll
        for (int i = 0; i < 4; i++) a[i] = As[(ty * 4 + i) * 97 + kk];
        #pragma unroll
        for (int j = 0; j < 6; j++) w[j] = bf2f(Wsm[(tx + 16 * j) * 97 + kk]);
        #pragma unroll
        for (int i = 0; i < 4; i++)
          #pragma unroll
          for (int j = 0; j < 6; j++) acc1[i][j] += a[i] * w[j];
      }
      #pragma unroll
      for (int i = 0; i < 4; i++)
        #pragma unroll
        for (int j = 0; j < 6; j++){
          float v = acc1[i][j] + fc1_b[c0 + tx + 16 * j];
          float ge = 0.5f * v * (1.f + erff(v * 0.70710678118f));
          Hs[(ty * 4 + i) * 97 + tx + 16 * j] = ge;
        }
    }
    __syncthreads();
    // stage fc2_w chunk (96 out rows, k = c0..c0+95) as bf16
    #pragma unroll
    for (int t = 0; t < 9; t++){
      int idx = t * 256 + tid;
      int r = idx / 24, c4 = idx - r * 24;
      float4 f = *reinterpret_cast<const float4*>(fc2_w + (size_t)r * 384 + c0 + c4 * 4);
      Wsm[r * 97 + c4 * 4 + 0] = f2bf(f.x);
      Wsm[r * 97 + c4 * 4 + 1] = f2bf(f.y);
      Wsm[r * 97 + c4 * 4 + 2] = f2bf(f.z);
      Wsm[r * 97 + c4 * 4 + 3] = f2bf(f.w);
    }
    __syncthreads();
    // fc2 microkernel accumulate
    for (int kk = 0; kk < 96; kk++){
      float a[4], w[6];
      #pragma unroll
      for (int i = 0; i < 4; i++) a[i] = Hs[(ty * 4 + i) * 97 + kk];
      #pragma unroll
      for (int j = 0; j < 6; j++) w[j] = bf2f(Wsm[(tx + 16 * j) * 97 + kk]);
      #pragma unroll
      for (int i = 0; i < 4; i++)
        #pragma unroll
        for (int j = 0; j < 6; j++) acc2[i][j] += a[i] * w[j];
    }
    __syncthreads();
  }

  #pragma unroll
  for (int i = 0; i < 4; i++){
    int r = row0 + ty * 4 + i;
    #pragma unroll
    for (int j = 0; j < 6; j++){
      int c = tx + 16 * j;
      out[(size_t)r * 96 + c] = acc2[i][j] + fc2_b[c] + bf2f(x2[(size_t)r * 96 + c]);
    }
  }
}

extern "C" void kernel_launch(void* const* d_in, const int* in_sizes, int n_in,
                              void* d_out, int out_size, void* d_ws, size_t ws_size,
                              hipStream_t stream)
{
  const float* x      = (const float*)d_in[0];
  const float* mask   = (const float*)d_in[1];
  const float* n1g    = (const float*)d_in[2];
  const float* n1b    = (const float*)d_in[3];
  const float* qkv_w  = (const float*)d_in[4];
  const float* qkv_b  = (const float*)d_in[5];
  const float* relt   = (const float*)d_in[6];
  const float* proj_w = (const float*)d_in[7];
  const float* proj_b = (const float*)d_in[8];
  const float* n2g    = (const float*)d_in[9];
  const float* n2b    = (const float*)d_in[10];
  const float* fc1_w  = (const float*)d_in[11];
  const float* fc1_b  = (const float*)d_in[12];
  const float* fc2_w  = (const float*)d_in[13];
  const float* fc2_b  = (const float*)d_in[14];
  float* outp = (float*)d_out;
  (void)in_sizes; (void)n_in; (void)out_size; (void)ws_size;

  const size_t M = 200704;
  char* ws = (char*)d_ws;
  unsigned short* qkvb  = (unsigned short*)ws;                 // M*288 bf16 = 115.6 MB
  size_t o = M * 288 * 2;
  unsigned short* x2    = (unsigned short*)(ws + o); o += M * 96 * 2;  // 38.5 MB
  float*          meanb = (float*)(ws + o); o += M * 4;
  float*          rstdb = (float*)(ws + o); o += M * 4;        // total ~155.7 MB

  // K1: LN1 stats (token order)
  ln_stats_kernel<<<50176, 256, 0, stream>>>(x, meanb, rstdb);
  // K2: QKV GEMM with fused LN1 + window gather -> qkvb bf16
  gemm_kernel<96, 288, 3, 0, 96><<<dim3(3, 3136), 256, 0, stream>>>(
      x, qkv_w, qkv_b, meanb, rstdb, n1g, n1b, nullptr, qkvb);
  // K3: windowed attention (in-place into q-slots)
  attn_kernel<<<4096, 256, 0, stream>>>(qkvb, mask, relt);
  // K4: proj GEMM + reverse-shift scatter + residual -> x2 bf16
  gemm_kernel<96, 96, 0, 2, 288><<<dim3(1, 3136), 256, 0, stream>>>(
      qkvb, proj_w, proj_b, nullptr, nullptr, nullptr, nullptr, x, x2);
  // K5: fused LN2 + fc1 + GELU + fc2 + residual -> out
  fused_mlp_kernel<<<3136, 256, 0, stream>>>(
      x2, n2g, n2b, fc1_w, fc1_b, fc2_w, fc2_b, outp);
}

// Round 3
// 999.432 us; speedup vs baseline: 2.7207x; 2.7207x over previous
//
#include <hip/hip_runtime.h>
#include <hip/hip_bf16.h>
#include <math.h>

// Swin block, MI355X round 2: MLP moved to bf16 MFMA; rest unchanged from the
// passing round-1 build. M=200704, C=96, heads=3, hd=32, WS=7, HID=384.

typedef __attribute__((ext_vector_type(8))) short bfrag8;   // 8 bf16 = 4 VGPRs
typedef __attribute__((ext_vector_type(4))) float f32x4;

__device__ __forceinline__ float bf2f(unsigned short u){
  union { unsigned int i; float f; } c; c.i = ((unsigned int)u) << 16; return c.f;
}
__device__ __forceinline__ unsigned short f2bf(float f){
  __hip_bfloat16 h = __float2bfloat16(f);
  union { __hip_bfloat16 h; unsigned short u; } c; c.h = h; return c.u;
}

// window-order row r (win*49+n) -> image row (b*12544 + h*112 + w), shift +3.
__device__ __forceinline__ int win_to_img(int r){
  int win = r / 49, n = r - win * 49;
  int b  = win >> 8, wi = win & 255;
  int wh = wi >> 4,  ww = wi & 15;
  int i  = n / 7,    j  = n - i * 7;
  int hs = wh * 7 + i + 3; if (hs >= 112) hs -= 112;
  int ws = ww * 7 + j + 3; if (ws >= 112) ws -= 112;
  return b * 12544 + hs * 112 + ws;
}

// ---- fp32 -> bf16 weight conversion (weights are L2-resident constants) ----
__global__ __launch_bounds__(256) void cvt_kernel(
    const float* __restrict__ src, unsigned short* __restrict__ dst, int n)
{
  int i = blockIdx.x * 256 + threadIdx.x;
  if (i < n) dst[i] = f2bf(src[i]);
}

// ---- LN1 row stats over x (token order) -------------------------------------
__global__ __launch_bounds__(256) void ln_stats_kernel(
    const float* __restrict__ x, float* __restrict__ mean_out, float* __restrict__ rstd_out)
{
  int lane = threadIdx.x & 63;
  int r = (blockIdx.x << 2) + (threadIdx.x >> 6);
  const float* row = x + (size_t)r * 96;
  float v0 = row[lane];
  float v1 = (lane < 32) ? row[64 + lane] : 0.f;
  float s = v0 + v1, q = v0 * v0 + v1 * v1;
  #pragma unroll
  for (int off = 32; off; off >>= 1){ s += __shfl_xor(s, off); q += __shfl_xor(q, off); }
  float mean = s * (1.f / 96.f);
  float var  = q * (1.f / 96.f) - mean * mean;
  if (lane == 0){ mean_out[r] = mean; rstd_out[r] = rsqrtf(var + 1e-5f); }
}

// ---- attention: one block per window, 3 heads; writes output into q-slots ---
__global__ __launch_bounds__(256) void attn_kernel(
    unsigned short* __restrict__ qkv, const float* __restrict__ mask,
    const float* __restrict__ relt)
{
  __shared__ float          qs[49 * 97];
  __shared__ unsigned short ks[49 * 100];
  __shared__ unsigned short vs[49 * 100];
  __shared__ float          S[147 * 50];
  int win = blockIdx.x;
  int tid = threadIdx.x;
  const float scale = 0.17677669529663687f;
  size_t base = (size_t)win * 49 * 288;
  for (int idx = tid; idx < 49 * 288; idx += 256){
    int n = idx / 288, c = idx - n * 288;
    unsigned short val = qkv[base + (size_t)n * 288 + c];
    int sect = c / 96, cc = c - sect * 96;
    if (sect == 0)      qs[n * 97  + cc] = bf2f(val) * scale;
    else if (sect == 1) ks[n * 100 + cc] = val;
    else                vs[n * 100 + cc] = val;
  }
  __syncthreads();
  int t = tid;
  if (t < 147){
    int hh = t / 49, p = t - hh * 49;
    float qr[32];
    #pragma unroll
    for (int d = 0; d < 32; d++) qr[d] = qs[p * 97 + hh * 32 + d];
    int i1 = p / 7, j1 = p - i1 * 7;
    const float* mrow = mask + (size_t)(win & 255) * 2401 + p * 49;
    float* Srow = S + t * 50;
    for (int m = 0; m < 49; m++){
      float dot = 0.f;
      #pragma unroll
      for (int d = 0; d < 32; d++) dot += qr[d] * bf2f(ks[m * 100 + hh * 32 + d]);
      int i2 = m / 7, j2 = m - i2 * 7;
      int ridx = (i1 - i2 + 6) * 13 + (j1 - j2 + 6);
      Srow[m] = dot + relt[ridx * 3 + hh] + mrow[m];
    }
    float mx = -1e30f;
    for (int m = 0; m < 49; m++) mx = fmaxf(mx, Srow[m]);
    float sum = 0.f;
    for (int m = 0; m < 49; m++){ float e = __expf(Srow[m] - mx); Srow[m] = e; sum += e; }
    float inv = 1.f / sum;
    float acc[32];
    #pragma unroll
    for (int d = 0; d < 32; d++) acc[d] = 0.f;
    for (int m = 0; m < 49; m++){
      float pm = Srow[m];
      #pragma unroll
      for (int d = 0; d < 32; d++) acc[d] += pm * bf2f(vs[m * 100 + hh * 32 + d]);
    }
    unsigned short* orow = qkv + base + (size_t)p * 288 + hh * 32;
    #pragma unroll
    for (int d = 0; d < 32; d++) orow[d] = f2bf(acc[d] * inv);
  }
}

// ---- generic tiled GEMM (unchanged, used for qkv + proj) --------------------
template<int K, int N, int AMODE, int OMODE, int ASTRIDE>
__global__ __launch_bounds__(256) void gemm_kernel(
    const void* __restrict__ Ap, const float* __restrict__ W, const float* __restrict__ bias,
    const float* __restrict__ mean, const float* __restrict__ rstd,
    const float* __restrict__ lng, const float* __restrict__ lnb,
    const float* __restrict__ resid, void* __restrict__ outp)
{
  __shared__ float As[64 * 17];
  __shared__ float Wsm[96 * 17];
  int tid = threadIdx.x;
  int tx = tid & 15, ty = tid >> 4;
  int row0 = blockIdx.y * 64;
  int col0 = blockIdx.x * 96;

  float acc[4][6];
  #pragma unroll
  for (int i = 0; i < 4; i++)
    #pragma unroll
    for (int j = 0; j < 6; j++) acc[i][j] = 0.f;

  int ar = tid >> 2;
  int ak = (tid & 3) * 4;
  float lm = 0.f, lr = 0.f;
  int gr = 0;
  if (AMODE == 3){ gr = win_to_img(row0 + ar); lm = mean[gr]; lr = rstd[gr]; }

  for (int k0 = 0; k0 < K; k0 += 16){
    if (AMODE == 0){
      const unsigned short* Abf = (const unsigned short*)Ap;
      ushort4 u = *reinterpret_cast<const ushort4*>(Abf + (size_t)(row0 + ar) * ASTRIDE + k0 + ak);
      As[ar * 17 + ak + 0] = bf2f(u.x);
      As[ar * 17 + ak + 1] = bf2f(u.y);
      As[ar * 17 + ak + 2] = bf2f(u.z);
      As[ar * 17 + ak + 3] = bf2f(u.w);
    } else {
      const float* Af = (const float*)Ap;
      float4 f = *reinterpret_cast<const float4*>(Af + (size_t)gr * 96 + k0 + ak);
      As[ar * 17 + ak + 0] = (f.x - lm) * lr * lng[k0 + ak + 0] + lnb[k0 + ak + 0];
      As[ar * 17 + ak + 1] = (f.y - lm) * lr * lng[k0 + ak + 1] + lnb[k0 + ak + 1];
      As[ar * 17 + ak + 2] = (f.z - lm) * lr * lng[k0 + ak + 2] + lnb[k0 + ak + 2];
      As[ar * 17 + ak + 3] = (f.w - lm) * lr * lng[k0 + ak + 3] + lnb[k0 + ak + 3];
    }
    #pragma unroll
    for (int t = 0; t < 6; t++){
      int idx = tid + 256 * t;
      int c = idx >> 4, kk = idx & 15;
      Wsm[c * 17 + kk] = W[(size_t)(col0 + c) * K + k0 + kk];
    }
    __syncthreads();
    #pragma unroll
    for (int kk = 0; kk < 16; kk++){
      float a[4], w[6];
      #pragma unroll
      for (int i = 0; i < 4; i++) a[i] = As[(ty * 4 + i) * 17 + kk];
      #pragma unroll
      for (int j = 0; j < 6; j++) w[j] = Wsm[(tx + 16 * j) * 17 + kk];
      #pragma unroll
      for (int i = 0; i < 4; i++)
        #pragma unroll
        for (int j = 0; j < 6; j++) acc[i][j] += a[i] * w[j];
    }
    __syncthreads();
  }

  #pragma unroll
  for (int i = 0; i < 4; i++){
    int r = row0 + ty * 4 + i;
    int orow = (OMODE == 2) ? win_to_img(r) : r;
    #pragma unroll
    for (int j = 0; j < 6; j++){
      int c = col0 + tx + 16 * j;
      float v = acc[i][j] + bias[c];
      if (OMODE == 0){
        ((unsigned short*)outp)[(size_t)r * N + c] = f2bf(v);
      } else {
        ((unsigned short*)outp)[(size_t)orow * 96 + c] =
            f2bf(v + resid[(size_t)orow * 96 + c]);
      }
    }
  }
}

// ---- MFMA MLP: LN2 + fc1 + GELU + fc2 + residual ----------------------------
// Block = 64 rows, 4 waves x 16-row M-tiles. B-frags stream from bf16 weights
// in global (L1/L2-resident). Hidden round-trips LDS (C/D -> A layout).
__global__ __launch_bounds__(256) void mlp_mfma_kernel(
    const unsigned short* __restrict__ x2,
    const float* __restrict__ g, const float* __restrict__ b,
    const unsigned short* __restrict__ w1, const float* __restrict__ b1,
    const unsigned short* __restrict__ w2, const float* __restrict__ b2,
    float* __restrict__ out)
{
  __shared__ unsigned short As[64 * 104];   // LN2(x2) bf16, row stride 104 (16B-mult)
  __shared__ unsigned short Hs[64 * 392];   // hidden bf16, row stride 392 (16B-mult)
  int tid = threadIdx.x;
  int row0 = blockIdx.x * 64;

  // stage x2 tile (bf16, raw)
  #pragma unroll
  for (int t = 0; t < 6; t++){
    int idx = t * 256 + tid;                // 1536 = 64 rows * 24 ushort4
    int r = idx / 24, c4 = (idx - r * 24) * 4;
    ushort4 u = *reinterpret_cast<const ushort4*>(x2 + (size_t)(row0 + r) * 96 + c4);
    *reinterpret_cast<ushort4*>(&As[r * 104 + c4]) = u;
  }
  __syncthreads();

  // LN2 in-place in As (4 threads per row)
  {
    int rr = tid >> 2, part = tid & 3;
    float v[24];
    float s = 0.f, q = 0.f;
    #pragma unroll
    for (int c = 0; c < 24; c++){
      v[c] = bf2f(As[rr * 104 + part * 24 + c]);
      s += v[c]; q += v[c] * v[c];
    }
    s += __shfl_xor(s, 1); q += __shfl_xor(q, 1);
    s += __shfl_xor(s, 2); q += __shfl_xor(q, 2);
    float mean = s * (1.f / 96.f);
    float rs = rsqrtf(q * (1.f / 96.f) - mean * mean + 1e-5f);
    #pragma unroll
    for (int c = 0; c < 24; c++){
      int cc = part * 24 + c;
      As[rr * 104 + cc] = f2bf((v[c] - mean) * rs * g[cc] + b[cc]);
    }
  }
  __syncthreads();

  int wave = tid >> 6, lane = tid & 63;
  int ln = lane & 15, qd = lane >> 4;
  int mrow = wave * 16;

  // A-frags for fc1 (K=96 -> 3 ksteps), kept in registers
  bfrag8 afrag[3];
  #pragma unroll
  for (int ks2 = 0; ks2 < 3; ks2++)
    afrag[ks2] = *reinterpret_cast<const bfrag8*>(&As[(mrow + ln) * 104 + ks2 * 32 + qd * 8]);

  // fc1 + bias + GELU -> Hs
  for (int nt = 0; nt < 24; nt++){
    f32x4 acc = {0.f, 0.f, 0.f, 0.f};
    #pragma unroll
    for (int ks2 = 0; ks2 < 3; ks2++){
      bfrag8 bfrag = *reinterpret_cast<const bfrag8*>(
          w1 + (size_t)(nt * 16 + ln) * 96 + ks2 * 32 + qd * 8);
      acc = __builtin_amdgcn_mfma_f32_16x16x32_bf16(afrag[ks2], bfrag, acc, 0, 0, 0);
    }
    int col = nt * 16 + ln;
    float bias = b1[col];
    #pragma unroll
    for (int r = 0; r < 4; r++){
      float vv = acc[r] + bias;
      float ge = 0.5f * vv * (1.f + erff(vv * 0.70710678118f));
      Hs[(mrow + qd * 4 + r) * 392 + col] = f2bf(ge);
    }
  }
  __syncthreads();

  // fc2: K=384 (12 ksteps), N=96 (6 ntiles), acc persists
  f32x4 acc2[6];
  #pragma unroll
  for (int nt = 0; nt < 6; nt++) acc2[nt] = (f32x4){0.f, 0.f, 0.f, 0.f};
  for (int ks2 = 0; ks2 < 12; ks2++){
    bfrag8 af = *reinterpret_cast<const bfrag8*>(&Hs[(mrow + ln) * 392 + ks2 * 32 + qd * 8]);
    #pragma unroll
    for (int nt = 0; nt < 6; nt++){
      bfrag8 bfrag = *reinterpret_cast<const bfrag8*>(
          w2 + (size_t)(nt * 16 + ln) * 384 + ks2 * 32 + qd * 8);
      acc2[nt] = __builtin_amdgcn_mfma_f32_16x16x32_bf16(af, bfrag, acc2[nt], 0, 0, 0);
    }
  }
  // epilogue: + fc2 bias + residual(x2) -> fp32 out
  #pragma unroll
  for (int nt = 0; nt < 6; nt++){
    int col = nt * 16 + ln;
    float bias = b2[col];
    #pragma unroll
    for (int r = 0; r < 4; r++){
      int grow = row0 + mrow + qd * 4 + r;
      out[(size_t)grow * 96 + col] = acc2[nt][r] + bias + bf2f(x2[(size_t)grow * 96 + col]);
    }
  }
}

extern "C" void kernel_launch(void* const* d_in, const int* in_sizes, int n_in,
                              void* d_out, int out_size, void* d_ws, size_t ws_size,
                              hipStream_t stream)
{
  const float* x      = (const float*)d_in[0];
  const float* mask   = (const float*)d_in[1];
  const float* n1g    = (const float*)d_in[2];
  const float* n1b    = (const float*)d_in[3];
  const float* qkv_w  = (const float*)d_in[4];
  const float* qkv_b  = (const float*)d_in[5];
  const float* relt   = (const float*)d_in[6];
  const float* proj_w = (const float*)d_in[7];
  const float* proj_b = (const float*)d_in[8];
  const float* n2g    = (const float*)d_in[9];
  const float* n2b    = (const float*)d_in[10];
  const float* fc1_w  = (const float*)d_in[11];
  const float* fc1_b  = (const float*)d_in[12];
  const float* fc2_w  = (const float*)d_in[13];
  const float* fc2_b  = (const float*)d_in[14];
  float* outp = (float*)d_out;
  (void)in_sizes; (void)n_in; (void)out_size; (void)ws_size;

  const size_t M = 200704;
  char* ws = (char*)d_ws;
  unsigned short* qkvb  = (unsigned short*)ws;                          // 115.6 MB
  size_t o = M * 288 * 2;
  unsigned short* x2    = (unsigned short*)(ws + o); o += M * 96 * 2;   // 38.5 MB
  float*          meanb = (float*)(ws + o); o += M * 4;
  float*          rstdb = (float*)(ws + o); o += M * 4;
  unsigned short* w1bf  = (unsigned short*)(ws + o); o += 384 * 96 * 2; // fc1_w bf16
  unsigned short* w2bf  = (unsigned short*)(ws + o); o += 96 * 384 * 2; // fc2_w bf16

  // K0: weight conversions (fp32 -> bf16)
  cvt_kernel<<<144, 256, 0, stream>>>(fc1_w, w1bf, 384 * 96);
  cvt_kernel<<<144, 256, 0, stream>>>(fc2_w, w2bf, 96 * 384);
  // K1: LN1 stats (token order)
  ln_stats_kernel<<<50176, 256, 0, stream>>>(x, meanb, rstdb);
  // K2: QKV GEMM with fused LN1 + window gather -> qkvb bf16
  gemm_kernel<96, 288, 3, 0, 96><<<dim3(3, 3136), 256, 0, stream>>>(
      x, qkv_w, qkv_b, meanb, rstdb, n1g, n1b, nullptr, qkvb);
  // K3: windowed attention (in-place into q-slots)
  attn_kernel<<<4096, 256, 0, stream>>>(qkvb, mask, relt);
  // K4: proj GEMM + reverse-shift scatter + residual -> x2 bf16
  gemm_kernel<96, 96, 0, 2, 288><<<dim3(1, 3136), 256, 0, stream>>>(
      qkvb, proj_w, proj_b, nullptr, nullptr, nullptr, nullptr, x, x2);
  // K5: MFMA MLP (LN2 + fc1 + GELU + fc2 + residual) -> out
  mlp_mfma_kernel<<<3136, 256, 0, stream>>>(
      x2, n2g, n2b, w1bf, fc1_b, w2bf, fc2_b, outp);
}

// Round 4
// 619.154 us; speedup vs baseline: 4.3918x; 1.6142x over previous
//
#include <hip/hip_runtime.h>
#include <hip/hip_bf16.h>
#include <math.h>

// Swin block, MI355X round 3: all GEMM-shaped work on bf16 MFMA
// (qkv, attention QK^T/PV, proj, mlp). M=200704, C=96, heads=3, hd=32, WS=7.

typedef __attribute__((ext_vector_type(8))) short bfrag8;   // 8 bf16 = 4 VGPRs
typedef __attribute__((ext_vector_type(4))) float f32x4;

__device__ __forceinline__ float bf2f(unsigned short u){
  union { unsigned int i; float f; } c; c.i = ((unsigned int)u) << 16; return c.f;
}
__device__ __forceinline__ unsigned short f2bf(float f){
  __hip_bfloat16 h = __float2bfloat16(f);
  union { __hip_bfloat16 h; unsigned short u; } c; c.h = h; return c.u;
}

// window-order row r (win*49+n) -> image row (b*12544 + h*112 + w), shift +3.
__device__ __forceinline__ int win_to_img(int r){
  int win = r / 49, n = r - win * 49;
  int b  = win >> 8, wi = win & 255;
  int wh = wi >> 4,  ww = wi & 15;
  int i  = n / 7,    j  = n - i * 7;
  int hs = wh * 7 + i + 3; if (hs >= 112) hs -= 112;
  int ws = ww * 7 + j + 3; if (ws >= 112) ws -= 112;
  return b * 12544 + hs * 112 + ws;
}

// ---- fp32 -> bf16 weight conversion ----------------------------------------
__global__ __launch_bounds__(256) void cvt_kernel(
    const float* __restrict__ src, unsigned short* __restrict__ dst, int n)
{
  int i = blockIdx.x * 256 + threadIdx.x;
  if (i < n) dst[i] = f2bf(src[i]);
}

// ---- combined rel-bias + shift-mask table: cb[w][h][m][n] fp32 --------------
__global__ __launch_bounds__(256) void cb_kernel(
    const float* __restrict__ relt, const float* __restrict__ mask,
    float* __restrict__ cb)
{
  int idx = blockIdx.x * 256 + threadIdx.x;
  if (idx >= 256 * 3 * 2401) return;
  int w = idx / 7203, rem = idx - w * 7203;
  int h = rem / 2401, mn = rem - h * 2401;
  int m = mn / 49, n = mn - m * 49;
  int i1 = m / 7, j1 = m - i1 * 7;
  int i2 = n / 7, j2 = n - i2 * 7;
  int ridx = (i1 - i2 + 6) * 13 + (j1 - j2 + 6);
  cb[idx] = relt[ridx * 3 + h] + mask[w * 2401 + mn];
}

// ---- LN1 row stats over x (token order) -------------------------------------
__global__ __launch_bounds__(256) void ln_stats_kernel(
    const float* __restrict__ x, float* __restrict__ mean_out, float* __restrict__ rstd_out)
{
  int lane = threadIdx.x & 63;
  int r = (blockIdx.x << 2) + (threadIdx.x >> 6);
  const float* row = x + (size_t)r * 96;
  float v0 = row[lane];
  float v1 = (lane < 32) ? row[64 + lane] : 0.f;
  float s = v0 + v1, q = v0 * v0 + v1 * v1;
  #pragma unroll
  for (int off = 32; off; off >>= 1){ s += __shfl_xor(s, off); q += __shfl_xor(q, off); }
  float mean = s * (1.f / 96.f);
  float var  = q * (1.f / 96.f) - mean * mean;
  if (lane == 0){ mean_out[r] = mean; rstd_out[r] = rsqrtf(var + 1e-5f); }
}

// ---- QKV GEMM (MFMA): A = LN1(gather(x)), B = qkv_w bf16 --------------------
__global__ __launch_bounds__(256) void qkv_mfma_kernel(
    const float* __restrict__ x, const float* __restrict__ mean,
    const float* __restrict__ rstd, const float* __restrict__ g,
    const float* __restrict__ b, const unsigned short* __restrict__ w,
    const float* __restrict__ bias, unsigned short* __restrict__ out)
{
  __shared__ unsigned short As[64 * 104];
  int tid = threadIdx.x;
  int row0 = blockIdx.x * 64;
  // stage: 4 threads/row, each 24 cols, LN1 fused, window gather
  {
    int r = tid >> 2, part = tid & 3;
    int gr = win_to_img(row0 + r);
    float lm = mean[gr], lr = rstd[gr];
    const float* rowp = x + (size_t)gr * 96 + part * 24;
    #pragma unroll
    for (int t = 0; t < 6; t++){
      float4 f = *reinterpret_cast<const float4*>(rowp + t * 4);
      int c = part * 24 + t * 4;
      ushort4 u;
      u.x = f2bf((f.x - lm) * lr * g[c + 0] + b[c + 0]);
      u.y = f2bf((f.y - lm) * lr * g[c + 1] + b[c + 1]);
      u.z = f2bf((f.z - lm) * lr * g[c + 2] + b[c + 2]);
      u.w = f2bf((f.w - lm) * lr * g[c + 3] + b[c + 3]);
      *reinterpret_cast<ushort4*>(&As[r * 104 + c]) = u;
    }
  }
  __syncthreads();
  int wave = tid >> 6, lane = tid & 63;
  int ln = lane & 15, qd = lane >> 4;
  int mrow = wave * 16;
  bfrag8 af[3];
  #pragma unroll
  for (int ks = 0; ks < 3; ks++)
    af[ks] = *reinterpret_cast<const bfrag8*>(&As[(mrow + ln) * 104 + ks * 32 + qd * 8]);
  for (int nt = 0; nt < 18; nt++){
    f32x4 acc = {0.f, 0.f, 0.f, 0.f};
    #pragma unroll
    for (int ks = 0; ks < 3; ks++){
      bfrag8 bf = *reinterpret_cast<const bfrag8*>(
          w + (size_t)(nt * 16 + ln) * 96 + ks * 32 + qd * 8);
      acc = __builtin_amdgcn_mfma_f32_16x16x32_bf16(af[ks], bf, acc, 0, 0, 0);
    }
    int col = nt * 16 + ln;
    float bs = bias[col];
    #pragma unroll
    for (int r = 0; r < 4; r++)
      out[(size_t)(row0 + mrow + qd * 4 + r) * 288 + col] = f2bf(acc[r] + bs);
  }
}

// ---- attention (MFMA): one block per window, waves 0-2 = heads --------------
__global__ __launch_bounds__(256) void attn_mfma_kernel(
    unsigned short* __restrict__ qkv, const float* __restrict__ cb)
{
  __shared__ unsigned short U[3 * 64 * 72];    // qs (3*64*40) overlaid by Ps (3*64*72)
  __shared__ unsigned short ks[3 * 64 * 40];
  __shared__ unsigned short vt[3 * 32 * 72];
  unsigned short* qs = U;
  unsigned short* Ps = U;
  int win = blockIdx.x;
  int tid = threadIdx.x;
  size_t base = (size_t)win * 49 * 288;
  const float scale = 0.17677669529663687f;

  // stage q (scaled), k, v^T
  for (int idx = tid; idx < 3528; idx += 256){
    int n = idx / 72, c4 = (idx - n * 72) * 4;
    ushort4 u = *reinterpret_cast<const ushort4*>(qkv + base + (size_t)n * 288 + c4);
    int sect = c4 / 96, cc = c4 - sect * 96;
    int h = cc >> 5, d = cc & 31;
    if (sect == 0){
      ushort4 uq;
      uq.x = f2bf(bf2f(u.x) * scale);
      uq.y = f2bf(bf2f(u.y) * scale);
      uq.z = f2bf(bf2f(u.z) * scale);
      uq.w = f2bf(bf2f(u.w) * scale);
      *reinterpret_cast<ushort4*>(&qs[h * 2560 + n * 40 + d]) = uq;
    } else if (sect == 1){
      *reinterpret_cast<ushort4*>(&ks[h * 2560 + n * 40 + d]) = u;
    } else {
      vt[h * 2304 + (d + 0) * 72 + n] = u.x;
      vt[h * 2304 + (d + 1) * 72 + n] = u.y;
      vt[h * 2304 + (d + 2) * 72 + n] = u.z;
      vt[h * 2304 + (d + 3) * 72 + n] = u.w;
    }
  }
  // zero pads: q/k rows 49..63 (k 0..31), vT cols 49..63
  for (int idx = tid; idx < 1440; idx += 256){
    int h = idx / 480, rem = idx - h * 480;
    int r = rem >> 5, k = rem & 31;
    qs[h * 2560 + (49 + r) * 40 + k] = 0;
    ks[h * 2560 + (49 + r) * 40 + k] = 0;
  }
  for (int idx = tid; idx < 1440; idx += 256){
    int h = idx / 480, rem = idx - h * 480;
    int d = rem / 15, kk = rem - d * 15;
    vt[h * 2304 + d * 72 + 49 + kk] = 0;
  }
  __syncthreads();

  int wave = tid >> 6, lane = tid & 63;
  int ln = lane & 15, qd = lane >> 4;
  int h = wave;

  bfrag8 qf[4];
  if (wave < 3){
    #pragma unroll
    for (int mt = 0; mt < 4; mt++)
      qf[mt] = *reinterpret_cast<const bfrag8*>(&qs[h * 2560 + (mt * 16 + ln) * 40 + qd * 8]);
  }
  __syncthreads();   // all q reads complete before P overwrites U

  f32x4 sf[4][4];
  if (wave < 3){
    const float* cbh = cb + ((size_t)(win & 255) * 3 + h) * 2401;
    #pragma unroll
    for (int nt = 0; nt < 4; nt++){
      bfrag8 kf = *reinterpret_cast<const bfrag8*>(&ks[h * 2560 + (nt * 16 + ln) * 40 + qd * 8]);
      #pragma unroll
      for (int mt = 0; mt < 4; mt++){
        f32x4 z = {0.f, 0.f, 0.f, 0.f};
        sf[mt][nt] = __builtin_amdgcn_mfma_f32_16x16x32_bf16(qf[mt], kf, z, 0, 0, 0);
      }
    }
    // bias + mask
    #pragma unroll
    for (int mt = 0; mt < 4; mt++)
      #pragma unroll
      for (int nt = 0; nt < 4; nt++)
        #pragma unroll
        for (int r = 0; r < 4; r++){
          int m = mt * 16 + qd * 4 + r, n = nt * 16 + ln;
          if (m < 49 && n < 49) sf[mt][nt][r] += cbh[m * 49 + n];
        }
    // softmax + P write (bf16)
    #pragma unroll
    for (int mt = 0; mt < 4; mt++){
      float mx[4], sm[4];
      #pragma unroll
      for (int r = 0; r < 4; r++){
        float v = fmaxf(fmaxf(sf[mt][0][r], sf[mt][1][r]), sf[mt][2][r]);
        if (ln == 0) v = fmaxf(v, sf[mt][3][r]);
        mx[r] = v;
      }
      #pragma unroll
      for (int r = 0; r < 4; r++)
        #pragma unroll
        for (int off = 1; off < 16; off <<= 1)
          mx[r] = fmaxf(mx[r], __shfl_xor(mx[r], off));
      #pragma unroll
      for (int r = 0; r < 4; r++){
        float e0 = __expf(sf[mt][0][r] - mx[r]);
        float e1 = __expf(sf[mt][1][r] - mx[r]);
        float e2 = __expf(sf[mt][2][r] - mx[r]);
        float e3 = (ln == 0) ? __expf(sf[mt][3][r] - mx[r]) : 0.f;
        sf[mt][0][r] = e0; sf[mt][1][r] = e1; sf[mt][2][r] = e2; sf[mt][3][r] = e3;
        sm[r] = e0 + e1 + e2 + e3;
      }
      #pragma unroll
      for (int r = 0; r < 4; r++)
        #pragma unroll
        for (int off = 1; off < 16; off <<= 1)
          sm[r] += __shfl_xor(sm[r], off);
      #pragma unroll
      for (int r = 0; r < 4; r++){
        float inv = 1.f / sm[r];
        int m = mt * 16 + qd * 4 + r;
        #pragma unroll
        for (int nt = 0; nt < 4; nt++)
          Ps[h * 4608 + m * 72 + nt * 16 + ln] = f2bf(sf[mt][nt][r] * inv);
      }
    }
  }
  __syncthreads();   // P visible (and Ps writes ordered vs any U reuse)

  if (wave < 3){
    f32x4 of[4][2];
    #pragma unroll
    for (int mt = 0; mt < 4; mt++)
      #pragma unroll
      for (int dt = 0; dt < 2; dt++) of[mt][dt] = (f32x4){0.f, 0.f, 0.f, 0.f};
    #pragma unroll
    for (int ks2 = 0; ks2 < 2; ks2++){
      bfrag8 vf[2];
      #pragma unroll
      for (int dt = 0; dt < 2; dt++)
        vf[dt] = *reinterpret_cast<const bfrag8*>(
            &vt[h * 2304 + (dt * 16 + ln) * 72 + ks2 * 32 + qd * 8]);
      #pragma unroll
      for (int mt = 0; mt < 4; mt++){
        bfrag8 pf = *reinterpret_cast<const bfrag8*>(
            &Ps[h * 4608 + (mt * 16 + ln) * 72 + ks2 * 32 + qd * 8]);
        #pragma unroll
        for (int dt = 0; dt < 2; dt++)
          of[mt][dt] = __builtin_amdgcn_mfma_f32_16x16x32_bf16(pf, vf[dt], of[mt][dt], 0, 0, 0);
      }
    }
    // write O into this window's q-slots
    #pragma unroll
    for (int mt = 0; mt < 4; mt++)
      #pragma unroll
      for (int r = 0; r < 4; r++){
        int m = mt * 16 + qd * 4 + r;
        if (m < 49){
          #pragma unroll
          for (int dt = 0; dt < 2; dt++)
            qkv[base + (size_t)m * 288 + h * 32 + dt * 16 + ln] = f2bf(of[mt][dt][r]);
        }
      }
  }
}

// ---- proj GEMM (MFMA) + reverse-shift scatter + residual -> x2 bf16 ---------
__global__ __launch_bounds__(256) void proj_mfma_kernel(
    const unsigned short* __restrict__ qkv, const unsigned short* __restrict__ w,
    const float* __restrict__ bias, const float* __restrict__ xres,
    unsigned short* __restrict__ x2)
{
  __shared__ unsigned short As[64 * 104];
  int tid = threadIdx.x;
  int row0 = blockIdx.x * 64;
  for (int idx = tid; idx < 1536; idx += 256){
    int r = idx / 24, c4 = (idx - r * 24) * 4;
    ushort4 u = *reinterpret_cast<const ushort4*>(qkv + (size_t)(row0 + r) * 288 + c4);
    *reinterpret_cast<ushort4*>(&As[r * 104 + c4]) = u;
  }
  __syncthreads();
  int wave = tid >> 6, lane = tid & 63;
  int ln = lane & 15, qd = lane >> 4;
  int mrow = wave * 16;
  bfrag8 af[3];
  #pragma unroll
  for (int ks = 0; ks < 3; ks++)
    af[ks] = *reinterpret_cast<const bfrag8*>(&As[(mrow + ln) * 104 + ks * 32 + qd * 8]);
  f32x4 accs[6];
  #pragma unroll
  for (int nt = 0; nt < 6; nt++){
    f32x4 acc = {0.f, 0.f, 0.f, 0.f};
    #pragma unroll
    for (int ks = 0; ks < 3; ks++){
      bfrag8 bf = *reinterpret_cast<const bfrag8*>(
          w + (size_t)(nt * 16 + ln) * 96 + ks * 32 + qd * 8);
      acc = __builtin_amdgcn_mfma_f32_16x16x32_bf16(af[ks], bf, acc, 0, 0, 0);
    }
    accs[nt] = acc;
  }
  #pragma unroll
  for (int r = 0; r < 4; r++){
    int gi = win_to_img(row0 + mrow + qd * 4 + r);
    #pragma unroll
    for (int nt = 0; nt < 6; nt++){
      int col = nt * 16 + ln;
      x2[(size_t)gi * 96 + col] =
          f2bf(accs[nt][r] + bias[col] + xres[(size_t)gi * 96 + col]);
    }
  }
}

// ---- MFMA MLP: LN2 + fc1 + GELU + fc2 + residual (unchanged) ----------------
__global__ __launch_bounds__(256) void mlp_mfma_kernel(
    const unsigned short* __restrict__ x2,
    const float* __restrict__ g, const float* __restrict__ b,
    const unsigned short* __restrict__ w1, const float* __restrict__ b1,
    const unsigned short* __restrict__ w2, const float* __restrict__ b2,
    float* __restrict__ out)
{
  __shared__ unsigned short As[64 * 104];
  __shared__ unsigned short Hs[64 * 392];
  int tid = threadIdx.x;
  int row0 = blockIdx.x * 64;
  #pragma unroll
  for (int t = 0; t < 6; t++){
    int idx = t * 256 + tid;
    int r = idx / 24, c4 = (idx - r * 24) * 4;
    ushort4 u = *reinterpret_cast<const ushort4*>(x2 + (size_t)(row0 + r) * 96 + c4);
    *reinterpret_cast<ushort4*>(&As[r * 104 + c4]) = u;
  }
  __syncthreads();
  {
    int rr = tid >> 2, part = tid & 3;
    float v[24];
    float s = 0.f, q = 0.f;
    #pragma unroll
    for (int c = 0; c < 24; c++){
      v[c] = bf2f(As[rr * 104 + part * 24 + c]);
      s += v[c]; q += v[c] * v[c];
    }
    s += __shfl_xor(s, 1); q += __shfl_xor(q, 1);
    s += __shfl_xor(s, 2); q += __shfl_xor(q, 2);
    float mean = s * (1.f / 96.f);
    float rs = rsqrtf(q * (1.f / 96.f) - mean * mean + 1e-5f);
    #pragma unroll
    for (int c = 0; c < 24; c++){
      int cc = part * 24 + c;
      As[rr * 104 + cc] = f2bf((v[c] - mean) * rs * g[cc] + b[cc]);
    }
  }
  __syncthreads();

  int wave = tid >> 6, lane = tid & 63;
  int ln = lane & 15, qd = lane >> 4;
  int mrow = wave * 16;

  bfrag8 afrag[3];
  #pragma unroll
  for (int ks2 = 0; ks2 < 3; ks2++)
    afrag[ks2] = *reinterpret_cast<const bfrag8*>(&As[(mrow + ln) * 104 + ks2 * 32 + qd * 8]);

  for (int nt = 0; nt < 24; nt++){
    f32x4 acc = {0.f, 0.f, 0.f, 0.f};
    #pragma unroll
    for (int ks2 = 0; ks2 < 3; ks2++){
      bfrag8 bfrag = *reinterpret_cast<const bfrag8*>(
          w1 + (size_t)(nt * 16 + ln) * 96 + ks2 * 32 + qd * 8);
      acc = __builtin_amdgcn_mfma_f32_16x16x32_bf16(afrag[ks2], bfrag, acc, 0, 0, 0);
    }
    int col = nt * 16 + ln;
    float bias = b1[col];
    #pragma unroll
    for (int r = 0; r < 4; r++){
      float vv = acc[r] + bias;
      float ge = 0.5f * vv * (1.f + erff(vv * 0.70710678118f));
      Hs[(mrow + qd * 4 + r) * 392 + col] = f2bf(ge);
    }
  }
  __syncthreads();

  f32x4 acc2[6];
  #pragma unroll
  for (int nt = 0; nt < 6; nt++) acc2[nt] = (f32x4){0.f, 0.f, 0.f, 0.f};
  for (int ks2 = 0; ks2 < 12; ks2++){
    bfrag8 af = *reinterpret_cast<const bfrag8*>(&Hs[(mrow + ln) * 392 + ks2 * 32 + qd * 8]);
    #pragma unroll
    for (int nt = 0; nt < 6; nt++){
      bfrag8 bfrag = *reinterpret_cast<const bfrag8*>(
          w2 + (size_t)(nt * 16 + ln) * 384 + ks2 * 32 + qd * 8);
      acc2[nt] = __builtin_amdgcn_mfma_f32_16x16x32_bf16(af, bfrag, acc2[nt], 0, 0, 0);
    }
  }
  #pragma unroll
  for (int nt = 0; nt < 6; nt++){
    int col = nt * 16 + ln;
    float bias = b2[col];
    #pragma unroll
    for (int r = 0; r < 4; r++){
      int grow = row0 + mrow + qd * 4 + r;
      out[(size_t)grow * 96 + col] = acc2[nt][r] + bias + bf2f(x2[(size_t)grow * 96 + col]);
    }
  }
}

extern "C" void kernel_launch(void* const* d_in, const int* in_sizes, int n_in,
                              void* d_out, int out_size, void* d_ws, size_t ws_size,
                              hipStream_t stream)
{
  const float* x      = (const float*)d_in[0];
  const float* mask   = (const float*)d_in[1];
  const float* n1g    = (const float*)d_in[2];
  const float* n1b    = (const float*)d_in[3];
  const float* qkv_w  = (const float*)d_in[4];
  const float* qkv_b  = (const float*)d_in[5];
  const float* relt   = (const float*)d_in[6];
  const float* proj_w = (const float*)d_in[7];
  const float* proj_b = (const float*)d_in[8];
  const float* n2g    = (const float*)d_in[9];
  const float* n2b    = (const float*)d_in[10];
  const float* fc1_w  = (const float*)d_in[11];
  const float* fc1_b  = (const float*)d_in[12];
  const float* fc2_w  = (const float*)d_in[13];
  const float* fc2_b  = (const float*)d_in[14];
  float* outp = (float*)d_out;
  (void)in_sizes; (void)n_in; (void)out_size; (void)ws_size;

  const size_t M = 200704;
  char* ws = (char*)d_ws;
  unsigned short* qkvb   = (unsigned short*)ws;                          // 115.6 MB
  size_t o = M * 288 * 2;
  unsigned short* x2     = (unsigned short*)(ws + o); o += M * 96 * 2;   // 38.5 MB
  float*          meanb  = (float*)(ws + o); o += M * 4;
  float*          rstdb  = (float*)(ws + o); o += M * 4;
  unsigned short* w1bf   = (unsigned short*)(ws + o); o += 384 * 96 * 2;
  unsigned short* w2bf   = (unsigned short*)(ws + o); o += 96 * 384 * 2;
  unsigned short* wqkvbf = (unsigned short*)(ws + o); o += 288 * 96 * 2;
  unsigned short* wprojbf= (unsigned short*)(ws + o); o += 96 * 96 * 2;
  float*          cbuf   = (float*)(ws + o); o += 256 * 3 * 2401 * 4;    // 7.4 MB

  // K0: weight conversions + combined bias table
  cvt_kernel<<<144, 256, 0, stream>>>(fc1_w, w1bf, 384 * 96);
  cvt_kernel<<<144, 256, 0, stream>>>(fc2_w, w2bf, 96 * 384);
  cvt_kernel<<<108, 256, 0, stream>>>(qkv_w, wqkvbf, 288 * 96);
  cvt_kernel<<<36, 256, 0, stream>>>(proj_w, wprojbf, 96 * 96);
  cb_kernel<<<7203, 256, 0, stream>>>(relt, mask, cbuf);
  // K1: LN1 stats (token order)
  ln_stats_kernel<<<50176, 256, 0, stream>>>(x, meanb, rstdb);
  // K2: QKV GEMM (MFMA, LN1-gather fused)
  qkv_mfma_kernel<<<3136, 256, 0, stream>>>(
      x, meanb, rstdb, n1g, n1b, wqkvbf, qkv_b, qkvb);
  // K3: attention (MFMA, in-place into q-slots)
  attn_mfma_kernel<<<4096, 256, 0, stream>>>(qkvb, cbuf);
  // K4: proj GEMM (MFMA) + reverse-shift scatter + residual
  proj_mfma_kernel<<<3136, 256, 0, stream>>>(qkvb, wprojbf, proj_b, x, x2);
  // K5: MFMA MLP
  mlp_mfma_kernel<<<3136, 256, 0, stream>>>(
      x2, n2g, n2b, w1bf, fc1_b, w2bf, fc2_b, outp);
}

// Round 5
// 603.127 us; speedup vs baseline: 4.5085x; 1.0266x over previous
//
#include <hip/hip_runtime.h>
#include <hip/hip_bf16.h>
#include <math.h>

// Swin block, MI355X round 4: MLP restructured for occupancy (25.6KB LDS via
// chunked hidden + As/Hs overlay, barrier-free wave-private inner loops).
// qkv/attn/proj unchanged from round 3. M=200704, C=96, heads=3, hd=32.

typedef __attribute__((ext_vector_type(8))) short bfrag8;   // 8 bf16 = 4 VGPRs
typedef __attribute__((ext_vector_type(4))) float f32x4;

__device__ __forceinline__ float bf2f(unsigned short u){
  union { unsigned int i; float f; } c; c.i = ((unsigned int)u) << 16; return c.f;
}
__device__ __forceinline__ unsigned short f2bf(float f){
  __hip_bfloat16 h = __float2bfloat16(f);
  union { __hip_bfloat16 h; unsigned short u; } c; c.h = h; return c.u;
}

// window-order row r (win*49+n) -> image row (b*12544 + h*112 + w), shift +3.
__device__ __forceinline__ int win_to_img(int r){
  int win = r / 49, n = r - win * 49;
  int b  = win >> 8, wi = win & 255;
  int wh = wi >> 4,  ww = wi & 15;
  int i  = n / 7,    j  = n - i * 7;
  int hs = wh * 7 + i + 3; if (hs >= 112) hs -= 112;
  int ws = ww * 7 + j + 3; if (ws >= 112) ws -= 112;
  return b * 12544 + hs * 112 + ws;
}

// ---- fp32 -> bf16 weight conversion ----------------------------------------
__global__ __launch_bounds__(256) void cvt_kernel(
    const float* __restrict__ src, unsigned short* __restrict__ dst, int n)
{
  int i = blockIdx.x * 256 + threadIdx.x;
  if (i < n) dst[i] = f2bf(src[i]);
}

// ---- combined rel-bias + shift-mask table: cb[w][h][m][n] fp32 --------------
__global__ __launch_bounds__(256) void cb_kernel(
    const float* __restrict__ relt, const float* __restrict__ mask,
    float* __restrict__ cb)
{
  int idx = blockIdx.x * 256 + threadIdx.x;
  if (idx >= 256 * 3 * 2401) return;
  int w = idx / 7203, rem = idx - w * 7203;
  int h = rem / 2401, mn = rem - h * 2401;
  int m = mn / 49, n = mn - m * 49;
  int i1 = m / 7, j1 = m - i1 * 7;
  int i2 = n / 7, j2 = n - i2 * 7;
  int ridx = (i1 - i2 + 6) * 13 + (j1 - j2 + 6);
  cb[idx] = relt[ridx * 3 + h] + mask[w * 2401 + mn];
}

// ---- LN1 row stats over x (token order) -------------------------------------
__global__ __launch_bounds__(256) void ln_stats_kernel(
    const float* __restrict__ x, float* __restrict__ mean_out, float* __restrict__ rstd_out)
{
  int lane = threadIdx.x & 63;
  int r = (blockIdx.x << 2) + (threadIdx.x >> 6);
  const float* row = x + (size_t)r * 96;
  float v0 = row[lane];
  float v1 = (lane < 32) ? row[64 + lane] : 0.f;
  float s = v0 + v1, q = v0 * v0 + v1 * v1;
  #pragma unroll
  for (int off = 32; off; off >>= 1){ s += __shfl_xor(s, off); q += __shfl_xor(q, off); }
  float mean = s * (1.f / 96.f);
  float var  = q * (1.f / 96.f) - mean * mean;
  if (lane == 0){ mean_out[r] = mean; rstd_out[r] = rsqrtf(var + 1e-5f); }
}

// ---- QKV GEMM (MFMA): A = LN1(gather(x)), B = qkv_w bf16 --------------------
__global__ __launch_bounds__(256) void qkv_mfma_kernel(
    const float* __restrict__ x, const float* __restrict__ mean,
    const float* __restrict__ rstd, const float* __restrict__ g,
    const float* __restrict__ b, const unsigned short* __restrict__ w,
    const float* __restrict__ bias, unsigned short* __restrict__ out)
{
  __shared__ unsigned short As[64 * 104];
  int tid = threadIdx.x;
  int row0 = blockIdx.x * 64;
  {
    int r = tid >> 2, part = tid & 3;
    int gr = win_to_img(row0 + r);
    float lm = mean[gr], lr = rstd[gr];
    const float* rowp = x + (size_t)gr * 96 + part * 24;
    #pragma unroll
    for (int t = 0; t < 6; t++){
      float4 f = *reinterpret_cast<const float4*>(rowp + t * 4);
      int c = part * 24 + t * 4;
      ushort4 u;
      u.x = f2bf((f.x - lm) * lr * g[c + 0] + b[c + 0]);
      u.y = f2bf((f.y - lm) * lr * g[c + 1] + b[c + 1]);
      u.z = f2bf((f.z - lm) * lr * g[c + 2] + b[c + 2]);
      u.w = f2bf((f.w - lm) * lr * g[c + 3] + b[c + 3]);
      *reinterpret_cast<ushort4*>(&As[r * 104 + c]) = u;
    }
  }
  __syncthreads();
  int wave = tid >> 6, lane = tid & 63;
  int ln = lane & 15, qd = lane >> 4;
  int mrow = wave * 16;
  bfrag8 af[3];
  #pragma unroll
  for (int ks = 0; ks < 3; ks++)
    af[ks] = *reinterpret_cast<const bfrag8*>(&As[(mrow + ln) * 104 + ks * 32 + qd * 8]);
  for (int nt = 0; nt < 18; nt++){
    f32x4 acc = {0.f, 0.f, 0.f, 0.f};
    #pragma unroll
    for (int ks = 0; ks < 3; ks++){
      bfrag8 bf = *reinterpret_cast<const bfrag8*>(
          w + (size_t)(nt * 16 + ln) * 96 + ks * 32 + qd * 8);
      acc = __builtin_amdgcn_mfma_f32_16x16x32_bf16(af[ks], bf, acc, 0, 0, 0);
    }
    int col = nt * 16 + ln;
    float bs = bias[col];
    #pragma unroll
    for (int r = 0; r < 4; r++)
      out[(size_t)(row0 + mrow + qd * 4 + r) * 288 + col] = f2bf(acc[r] + bs);
  }
}

// ---- attention (MFMA): one block per window, waves 0-2 = heads --------------
__global__ __launch_bounds__(256) void attn_mfma_kernel(
    unsigned short* __restrict__ qkv, const float* __restrict__ cb)
{
  __shared__ unsigned short U[3 * 64 * 72];    // qs (3*64*40) overlaid by Ps (3*64*72)
  __shared__ unsigned short ks[3 * 64 * 40];
  __shared__ unsigned short vt[3 * 32 * 72];
  unsigned short* qs = U;
  unsigned short* Ps = U;
  int win = blockIdx.x;
  int tid = threadIdx.x;
  size_t base = (size_t)win * 49 * 288;
  const float scale = 0.17677669529663687f;

  for (int idx = tid; idx < 3528; idx += 256){
    int n = idx / 72, c4 = (idx - n * 72) * 4;
    ushort4 u = *reinterpret_cast<const ushort4*>(qkv + base + (size_t)n * 288 + c4);
    int sect = c4 / 96, cc = c4 - sect * 96;
    int h = cc >> 5, d = cc & 31;
    if (sect == 0){
      ushort4 uq;
      uq.x = f2bf(bf2f(u.x) * scale);
      uq.y = f2bf(bf2f(u.y) * scale);
      uq.z = f2bf(bf2f(u.z) * scale);
      uq.w = f2bf(bf2f(u.w) * scale);
      *reinterpret_cast<ushort4*>(&qs[h * 2560 + n * 40 + d]) = uq;
    } else if (sect == 1){
      *reinterpret_cast<ushort4*>(&ks[h * 2560 + n * 40 + d]) = u;
    } else {
      vt[h * 2304 + (d + 0) * 72 + n] = u.x;
      vt[h * 2304 + (d + 1) * 72 + n] = u.y;
      vt[h * 2304 + (d + 2) * 72 + n] = u.z;
      vt[h * 2304 + (d + 3) * 72 + n] = u.w;
    }
  }
  for (int idx = tid; idx < 1440; idx += 256){
    int h = idx / 480, rem = idx - h * 480;
    int r = rem >> 5, k = rem & 31;
    qs[h * 2560 + (49 + r) * 40 + k] = 0;
    ks[h * 2560 + (49 + r) * 40 + k] = 0;
  }
  for (int idx = tid; idx < 1440; idx += 256){
    int h = idx / 480, rem = idx - h * 480;
    int d = rem / 15, kk = rem - d * 15;
    vt[h * 2304 + d * 72 + 49 + kk] = 0;
  }
  __syncthreads();

  int wave = tid >> 6, lane = tid & 63;
  int ln = lane & 15, qd = lane >> 4;
  int h = wave;

  bfrag8 qf[4];
  if (wave < 3){
    #pragma unroll
    for (int mt = 0; mt < 4; mt++)
      qf[mt] = *reinterpret_cast<const bfrag8*>(&qs[h * 2560 + (mt * 16 + ln) * 40 + qd * 8]);
  }
  __syncthreads();

  f32x4 sf[4][4];
  if (wave < 3){
    const float* cbh = cb + ((size_t)(win & 255) * 3 + h) * 2401;
    #pragma unroll
    for (int nt = 0; nt < 4; nt++){
      bfrag8 kf = *reinterpret_cast<const bfrag8*>(&ks[h * 2560 + (nt * 16 + ln) * 40 + qd * 8]);
      #pragma unroll
      for (int mt = 0; mt < 4; mt++){
        f32x4 z = {0.f, 0.f, 0.f, 0.f};
        sf[mt][nt] = __builtin_amdgcn_mfma_f32_16x16x32_bf16(qf[mt], kf, z, 0, 0, 0);
      }
    }
    #pragma unroll
    for (int mt = 0; mt < 4; mt++)
      #pragma unroll
      for (int nt = 0; nt < 4; nt++)
        #pragma unroll
        for (int r = 0; r < 4; r++){
          int m = mt * 16 + qd * 4 + r, n = nt * 16 + ln;
          if (m < 49 && n < 49) sf[mt][nt][r] += cbh[m * 49 + n];
        }
    #pragma unroll
    for (int mt = 0; mt < 4; mt++){
      float mx[4], sm[4];
      #pragma unroll
      for (int r = 0; r < 4; r++){
        float v = fmaxf(fmaxf(sf[mt][0][r], sf[mt][1][r]), sf[mt][2][r]);
        if (ln == 0) v = fmaxf(v, sf[mt][3][r]);
        mx[r] = v;
      }
      #pragma unroll
      for (int r = 0; r < 4; r++)
        #pragma unroll
        for (int off = 1; off < 16; off <<= 1)
          mx[r] = fmaxf(mx[r], __shfl_xor(mx[r], off));
      #pragma unroll
      for (int r = 0; r < 4; r++){
        float e0 = __expf(sf[mt][0][r] - mx[r]);
        float e1 = __expf(sf[mt][1][r] - mx[r]);
        float e2 = __expf(sf[mt][2][r] - mx[r]);
        float e3 = (ln == 0) ? __expf(sf[mt][3][r] - mx[r]) : 0.f;
        sf[mt][0][r] = e0; sf[mt][1][r] = e1; sf[mt][2][r] = e2; sf[mt][3][r] = e3;
        sm[r] = e0 + e1 + e2 + e3;
      }
      #pragma unroll
      for (int r = 0; r < 4; r++)
        #pragma unroll
        for (int off = 1; off < 16; off <<= 1)
          sm[r] += __shfl_xor(sm[r], off);
      #pragma unroll
      for (int r = 0; r < 4; r++){
        float inv = 1.f / sm[r];
        int m = mt * 16 + qd * 4 + r;
        #pragma unroll
        for (int nt = 0; nt < 4; nt++)
          Ps[h * 4608 + m * 72 + nt * 16 + ln] = f2bf(sf[mt][nt][r] * inv);
      }
    }
  }
  __syncthreads();

  if (wave < 3){
    f32x4 of[4][2];
    #pragma unroll
    for (int mt = 0; mt < 4; mt++)
      #pragma unroll
      for (int dt = 0; dt < 2; dt++) of[mt][dt] = (f32x4){0.f, 0.f, 0.f, 0.f};
    #pragma unroll
    for (int ks2 = 0; ks2 < 2; ks2++){
      bfrag8 vf[2];
      #pragma unroll
      for (int dt = 0; dt < 2; dt++)
        vf[dt] = *reinterpret_cast<const bfrag8*>(
            &vt[h * 2304 + (dt * 16 + ln) * 72 + ks2 * 32 + qd * 8]);
      #pragma unroll
      for (int mt = 0; mt < 4; mt++){
        bfrag8 pf = *reinterpret_cast<const bfrag8*>(
            &Ps[h * 4608 + (mt * 16 + ln) * 72 + ks2 * 32 + qd * 8]);
        #pragma unroll
        for (int dt = 0; dt < 2; dt++)
          of[mt][dt] = __builtin_amdgcn_mfma_f32_16x16x32_bf16(pf, vf[dt], of[mt][dt], 0, 0, 0);
      }
    }
    #pragma unroll
    for (int mt = 0; mt < 4; mt++)
      #pragma unroll
      for (int r = 0; r < 4; r++){
        int m = mt * 16 + qd * 4 + r;
        if (m < 49){
          #pragma unroll
          for (int dt = 0; dt < 2; dt++)
            qkv[base + (size_t)m * 288 + h * 32 + dt * 16 + ln] = f2bf(of[mt][dt][r]);
        }
      }
  }
}

// ---- proj GEMM (MFMA) + reverse-shift scatter + residual -> x2 bf16 ---------
__global__ __launch_bounds__(256) void proj_mfma_kernel(
    const unsigned short* __restrict__ qkv, const unsigned short* __restrict__ w,
    const float* __restrict__ bias, const float* __restrict__ xres,
    unsigned short* __restrict__ x2)
{
  __shared__ unsigned short As[64 * 104];
  int tid = threadIdx.x;
  int row0 = blockIdx.x * 64;
  for (int idx = tid; idx < 1536; idx += 256){
    int r = idx / 24, c4 = (idx - r * 24) * 4;
    ushort4 u = *reinterpret_cast<const ushort4*>(qkv + (size_t)(row0 + r) * 288 + c4);
    *reinterpret_cast<ushort4*>(&As[r * 104 + c4]) = u;
  }
  __syncthreads();
  int wave = tid >> 6, lane = tid & 63;
  int ln = lane & 15, qd = lane >> 4;
  int mrow = wave * 16;
  bfrag8 af[3];
  #pragma unroll
  for (int ks = 0; ks < 3; ks++)
    af[ks] = *reinterpret_cast<const bfrag8*>(&As[(mrow + ln) * 104 + ks * 32 + qd * 8]);
  f32x4 accs[6];
  #pragma unroll
  for (int nt = 0; nt < 6; nt++){
    f32x4 acc = {0.f, 0.f, 0.f, 0.f};
    #pragma unroll
    for (int ks = 0; ks < 3; ks++){
      bfrag8 bf = *reinterpret_cast<const bfrag8*>(
          w + (size_t)(nt * 16 + ln) * 96 + ks * 32 + qd * 8);
      acc = __builtin_amdgcn_mfma_f32_16x16x32_bf16(af[ks], bf, acc, 0, 0, 0);
    }
    accs[nt] = acc;
  }
  #pragma unroll
  for (int r = 0; r < 4; r++){
    int gi = win_to_img(row0 + mrow + qd * 4 + r);
    #pragma unroll
    for (int nt = 0; nt < 6; nt++){
      int col = nt * 16 + ln;
      x2[(size_t)gi * 96 + col] =
          f2bf(accs[nt][r] + bias[col] + xres[(size_t)gi * 96 + col]);
    }
  }
}

// ---- MFMA MLP: LN2 + fc1 + GELU + fc2 + residual ----------------------------
// 25.6KB LDS: hidden processed in two 192-wide chunks; As overlays Hs (As is
// dead after A-frags land in registers). After the afrag barrier, each wave's
// Hs rows are private -> no further __syncthreads().
__global__ __launch_bounds__(256, 5) void mlp_mfma_kernel(
    const unsigned short* __restrict__ x2,
    const float* __restrict__ g, const float* __restrict__ b,
    const unsigned short* __restrict__ w1, const float* __restrict__ b1,
    const unsigned short* __restrict__ w2, const float* __restrict__ b2,
    float* __restrict__ out)
{
  __shared__ unsigned short Hs[64 * 200];   // 25.6 KB; As overlays (stride 104)
  unsigned short* As = Hs;
  int tid = threadIdx.x;
  int row0 = blockIdx.x * 64;

  #pragma unroll
  for (int t = 0; t < 6; t++){
    int idx = t * 256 + tid;
    int r = idx / 24, c4 = (idx - r * 24) * 4;
    ushort4 u = *reinterpret_cast<const ushort4*>(x2 + (size_t)(row0 + r) * 96 + c4);
    *reinterpret_cast<ushort4*>(&As[r * 104 + c4]) = u;
  }
  __syncthreads();
  {
    int rr = tid >> 2, part = tid & 3;
    float v[24];
    float s = 0.f, q = 0.f;
    #pragma unroll
    for (int c = 0; c < 24; c++){
      v[c] = bf2f(As[rr * 104 + part * 24 + c]);
      s += v[c]; q += v[c] * v[c];
    }
    s += __shfl_xor(s, 1); q += __shfl_xor(q, 1);
    s += __shfl_xor(s, 2); q += __shfl_xor(q, 2);
    float mean = s * (1.f / 96.f);
    float rs = rsqrtf(q * (1.f / 96.f) - mean * mean + 1e-5f);
    #pragma unroll
    for (int c = 0; c < 24; c++){
      int cc = part * 24 + c;
      As[rr * 104 + cc] = f2bf((v[c] - mean) * rs * g[cc] + b[cc]);
    }
  }
  __syncthreads();

  int wave = tid >> 6, lane = tid & 63;
  int ln = lane & 15, qd = lane >> 4;
  int mrow = wave * 16;

  bfrag8 afrag[3];
  #pragma unroll
  for (int ks2 = 0; ks2 < 3; ks2++)
    afrag[ks2] = *reinterpret_cast<const bfrag8*>(&As[(mrow + ln) * 104 + ks2 * 32 + qd * 8]);
  __syncthreads();   // As consumed by ALL waves; Hs writes may now overwrite it

  f32x4 acc2[6];
  #pragma unroll
  for (int nt = 0; nt < 6; nt++) acc2[nt] = (f32x4){0.f, 0.f, 0.f, 0.f};

  #pragma unroll
  for (int chunk = 0; chunk < 2; chunk++){
    // fc1 half: hidden cols [chunk*192, chunk*192+192) -> Hs (wave-private rows)
    for (int ntl = 0; ntl < 12; ntl++){
      f32x4 acc = {0.f, 0.f, 0.f, 0.f};
      int colg = chunk * 192 + ntl * 16 + ln;
      #pragma unroll
      for (int ks2 = 0; ks2 < 3; ks2++){
        bfrag8 bfrag = *reinterpret_cast<const bfrag8*>(
            w1 + (size_t)colg * 96 + ks2 * 32 + qd * 8);
        acc = __builtin_amdgcn_mfma_f32_16x16x32_bf16(afrag[ks2], bfrag, acc, 0, 0, 0);
      }
      float bias = b1[colg];
      #pragma unroll
      for (int r = 0; r < 4; r++){
        float vv = acc[r] + bias;
        float ge = 0.5f * vv * (1.f + erff(vv * 0.70710678118f));
        Hs[(mrow + qd * 4 + r) * 200 + ntl * 16 + ln] = f2bf(ge);
      }
    }
    // fc2 half: K slice [chunk*192, +192) (wave-private Hs rows; no barrier)
    for (int ks2 = 0; ks2 < 6; ks2++){
      bfrag8 pf = *reinterpret_cast<const bfrag8*>(&Hs[(mrow + ln) * 200 + ks2 * 32 + qd * 8]);
      #pragma unroll
      for (int nt = 0; nt < 6; nt++){
        bfrag8 bfrag = *reinterpret_cast<const bfrag8*>(
            w2 + (size_t)(nt * 16 + ln) * 384 + chunk * 192 + ks2 * 32 + qd * 8);
        acc2[nt] = __builtin_amdgcn_mfma_f32_16x16x32_bf16(pf, bfrag, acc2[nt], 0, 0, 0);
      }
    }
  }

  #pragma unroll
  for (int nt = 0; nt < 6; nt++){
    int col = nt * 16 + ln;
    float bias = b2[col];
    #pragma unroll
    for (int r = 0; r < 4; r++){
      int grow = row0 + mrow + qd * 4 + r;
      out[(size_t)grow * 96 + col] = acc2[nt][r] + bias + bf2f(x2[(size_t)grow * 96 + col]);
    }
  }
}

extern "C" void kernel_launch(void* const* d_in, const int* in_sizes, int n_in,
                              void* d_out, int out_size, void* d_ws, size_t ws_size,
                              hipStream_t stream)
{
  const float* x      = (const float*)d_in[0];
  const float* mask   = (const float*)d_in[1];
  const float* n1g    = (const float*)d_in[2];
  const float* n1b    = (const float*)d_in[3];
  const float* qkv_w  = (const float*)d_in[4];
  const float* qkv_b  = (const float*)d_in[5];
  const float* relt   = (const float*)d_in[6];
  const float* proj_w = (const float*)d_in[7];
  const float* proj_b = (const float*)d_in[8];
  const float* n2g    = (const float*)d_in[9];
  const float* n2b    = (const float*)d_in[10];
  const float* fc1_w  = (const float*)d_in[11];
  const float* fc1_b  = (const float*)d_in[12];
  const float* fc2_w  = (const float*)d_in[13];
  const float* fc2_b  = (const float*)d_in[14];
  float* outp = (float*)d_out;
  (void)in_sizes; (void)n_in; (void)out_size; (void)ws_size;

  const size_t M = 200704;
  char* ws = (char*)d_ws;
  unsigned short* qkvb   = (unsigned short*)ws;                          // 115.6 MB
  size_t o = M * 288 * 2;
  unsigned short* x2     = (unsigned short*)(ws + o); o += M * 96 * 2;   // 38.5 MB
  float*          meanb  = (float*)(ws + o); o += M * 4;
  float*          rstdb  = (float*)(ws + o); o += M * 4;
  unsigned short* w1bf   = (unsigned short*)(ws + o); o += 384 * 96 * 2;
  unsigned short* w2bf   = (unsigned short*)(ws + o); o += 96 * 384 * 2;
  unsigned short* wqkvbf = (unsigned short*)(ws + o); o += 288 * 96 * 2;
  unsigned short* wprojbf= (unsigned short*)(ws + o); o += 96 * 96 * 2;
  float*          cbuf   = (float*)(ws + o); o += 256 * 3 * 2401 * 4;    // 7.4 MB

  cvt_kernel<<<144, 256, 0, stream>>>(fc1_w, w1bf, 384 * 96);
  cvt_kernel<<<144, 256, 0, stream>>>(fc2_w, w2bf, 96 * 384);
  cvt_kernel<<<108, 256, 0, stream>>>(qkv_w, wqkvbf, 288 * 96);
  cvt_kernel<<<36, 256, 0, stream>>>(proj_w, wprojbf, 96 * 96);
  cb_kernel<<<7203, 256, 0, stream>>>(relt, mask, cbuf);
  ln_stats_kernel<<<50176, 256, 0, stream>>>(x, meanb, rstdb);
  qkv_mfma_kernel<<<3136, 256, 0, stream>>>(
      x, meanb, rstdb, n1g, n1b, wqkvbf, qkv_b, qkvb);
  attn_mfma_kernel<<<4096, 256, 0, stream>>>(qkvb, cbuf);
  proj_mfma_kernel<<<3136, 256, 0, stream>>>(qkvb, wprojbf, proj_b, x, x2);
  mlp_mfma_kernel<<<3136, 256, 0, stream>>>(
      x2, n2g, n2b, w1bf, fc1_b, w2bf, fc2_b, outp);
}

// Round 6
// 507.845 us; speedup vs baseline: 5.3543x; 1.1876x over previous
//
#include <hip/hip_runtime.h>
#include <hip/hip_bf16.h>
#include <math.h>

// Swin block, MI355X round 5: ILP restructure of the three streaming GEMMs
// (mlp/qkv/proj): 128-row blocks, 2 M-tiles per wave (2 MFMAs per B-frag
// load), launch_bounds(256,4) so the compiler can prefetch B-frags.
// attn unchanged. M=200704, C=96, heads=3, hd=32, WS=7, HID=384.

typedef __attribute__((ext_vector_type(8))) short bfrag8;   // 8 bf16 = 4 VGPRs
typedef __attribute__((ext_vector_type(4))) float f32x4;

__device__ __forceinline__ float bf2f(unsigned short u){
  union { unsigned int i; float f; } c; c.i = ((unsigned int)u) << 16; return c.f;
}
__device__ __forceinline__ unsigned short f2bf(float f){
  __hip_bfloat16 h = __float2bfloat16(f);
  union { __hip_bfloat16 h; unsigned short u; } c; c.h = h; return c.u;
}

// window-order row r (win*49+n) -> image row (b*12544 + h*112 + w), shift +3.
__device__ __forceinline__ int win_to_img(int r){
  int win = r / 49, n = r - win * 49;
  int b  = win >> 8, wi = win & 255;
  int wh = wi >> 4,  ww = wi & 15;
  int i  = n / 7,    j  = n - i * 7;
  int hs = wh * 7 + i + 3; if (hs >= 112) hs -= 112;
  int ws = ww * 7 + j + 3; if (ws >= 112) ws -= 112;
  return b * 12544 + hs * 112 + ws;
}

// ---- fp32 -> bf16 weight conversion ----------------------------------------
__global__ __launch_bounds__(256) void cvt_kernel(
    const float* __restrict__ src, unsigned short* __restrict__ dst, int n)
{
  int i = blockIdx.x * 256 + threadIdx.x;
  if (i < n) dst[i] = f2bf(src[i]);
}

// ---- combined rel-bias + shift-mask table: cb[w][h][m][n] fp32 --------------
__global__ __launch_bounds__(256) void cb_kernel(
    const float* __restrict__ relt, const float* __restrict__ mask,
    float* __restrict__ cb)
{
  int idx = blockIdx.x * 256 + threadIdx.x;
  if (idx >= 256 * 3 * 2401) return;
  int w = idx / 7203, rem = idx - w * 7203;
  int h = rem / 2401, mn = rem - h * 2401;
  int m = mn / 49, n = mn - m * 49;
  int i1 = m / 7, j1 = m - i1 * 7;
  int i2 = n / 7, j2 = n - i2 * 7;
  int ridx = (i1 - i2 + 6) * 13 + (j1 - j2 + 6);
  cb[idx] = relt[ridx * 3 + h] + mask[w * 2401 + mn];
}

// ---- LN1 row stats over x (token order) -------------------------------------
__global__ __launch_bounds__(256) void ln_stats_kernel(
    const float* __restrict__ x, float* __restrict__ mean_out, float* __restrict__ rstd_out)
{
  int lane = threadIdx.x & 63;
  int r = (blockIdx.x << 2) + (threadIdx.x >> 6);
  const float* row = x + (size_t)r * 96;
  float v0 = row[lane];
  float v1 = (lane < 32) ? row[64 + lane] : 0.f;
  float s = v0 + v1, q = v0 * v0 + v1 * v1;
  #pragma unroll
  for (int off = 32; off; off >>= 1){ s += __shfl_xor(s, off); q += __shfl_xor(q, off); }
  float mean = s * (1.f / 96.f);
  float var  = q * (1.f / 96.f) - mean * mean;
  if (lane == 0){ mean_out[r] = mean; rstd_out[r] = rsqrtf(var + 1e-5f); }
}

// ---- QKV GEMM (MFMA): 128-row blocks, 2 M-tiles/wave ------------------------
__global__ __launch_bounds__(256, 4) void qkv_mfma_kernel(
    const float* __restrict__ x, const float* __restrict__ mean,
    const float* __restrict__ rstd, const float* __restrict__ g,
    const float* __restrict__ b, const unsigned short* __restrict__ w,
    const float* __restrict__ bias, unsigned short* __restrict__ out)
{
  __shared__ unsigned short As[128 * 104];
  int tid = threadIdx.x;
  int row0 = blockIdx.x * 128;
  {
    int r = tid >> 1, part = tid & 1;
    int gr = win_to_img(row0 + r);
    float lm = mean[gr], lr = rstd[gr];
    const float* rowp = x + (size_t)gr * 96 + part * 48;
    #pragma unroll
    for (int t = 0; t < 12; t++){
      float4 f = *reinterpret_cast<const float4*>(rowp + t * 4);
      int c = part * 48 + t * 4;
      ushort4 u;
      u.x = f2bf((f.x - lm) * lr * g[c + 0] + b[c + 0]);
      u.y = f2bf((f.y - lm) * lr * g[c + 1] + b[c + 1]);
      u.z = f2bf((f.z - lm) * lr * g[c + 2] + b[c + 2]);
      u.w = f2bf((f.w - lm) * lr * g[c + 3] + b[c + 3]);
      *reinterpret_cast<ushort4*>(&As[r * 104 + c]) = u;
    }
  }
  __syncthreads();
  int wave = tid >> 6, lane = tid & 63;
  int ln = lane & 15, qd = lane >> 4;
  int mrow = wave * 32;
  bfrag8 af[2][3];
  #pragma unroll
  for (int mt = 0; mt < 2; mt++)
    #pragma unroll
    for (int ks = 0; ks < 3; ks++)
      af[mt][ks] = *reinterpret_cast<const bfrag8*>(
          &As[(mrow + mt * 16 + ln) * 104 + ks * 32 + qd * 8]);
  for (int nt = 0; nt < 18; nt++){
    int col = nt * 16 + ln;
    const unsigned short* wp = w + (size_t)col * 96 + qd * 8;
    bfrag8 B0 = *reinterpret_cast<const bfrag8*>(wp);
    bfrag8 B1 = *reinterpret_cast<const bfrag8*>(wp + 32);
    bfrag8 B2 = *reinterpret_cast<const bfrag8*>(wp + 64);
    f32x4 a0 = {0.f,0.f,0.f,0.f}, a1 = {0.f,0.f,0.f,0.f};
    a0 = __builtin_amdgcn_mfma_f32_16x16x32_bf16(af[0][0], B0, a0, 0, 0, 0);
    a1 = __builtin_amdgcn_mfma_f32_16x16x32_bf16(af[1][0], B0, a1, 0, 0, 0);
    a0 = __builtin_amdgcn_mfma_f32_16x16x32_bf16(af[0][1], B1, a0, 0, 0, 0);
    a1 = __builtin_amdgcn_mfma_f32_16x16x32_bf16(af[1][1], B1, a1, 0, 0, 0);
    a0 = __builtin_amdgcn_mfma_f32_16x16x32_bf16(af[0][2], B2, a0, 0, 0, 0);
    a1 = __builtin_amdgcn_mfma_f32_16x16x32_bf16(af[1][2], B2, a1, 0, 0, 0);
    float bs = bias[col];
    #pragma unroll
    for (int r = 0; r < 4; r++){
      out[(size_t)(row0 + mrow + qd * 4 + r) * 288 + col] = f2bf(a0[r] + bs);
      out[(size_t)(row0 + mrow + 16 + qd * 4 + r) * 288 + col] = f2bf(a1[r] + bs);
    }
  }
}

// ---- attention (MFMA): one block per window, waves 0-2 = heads (unchanged) --
__global__ __launch_bounds__(256) void attn_mfma_kernel(
    unsigned short* __restrict__ qkv, const float* __restrict__ cb)
{
  __shared__ unsigned short U[3 * 64 * 72];
  __shared__ unsigned short ks[3 * 64 * 40];
  __shared__ unsigned short vt[3 * 32 * 72];
  unsigned short* qs = U;
  unsigned short* Ps = U;
  int win = blockIdx.x;
  int tid = threadIdx.x;
  size_t base = (size_t)win * 49 * 288;
  const float scale = 0.17677669529663687f;

  for (int idx = tid; idx < 3528; idx += 256){
    int n = idx / 72, c4 = (idx - n * 72) * 4;
    ushort4 u = *reinterpret_cast<const ushort4*>(qkv + base + (size_t)n * 288 + c4);
    int sect = c4 / 96, cc = c4 - sect * 96;
    int h = cc >> 5, d = cc & 31;
    if (sect == 0){
      ushort4 uq;
      uq.x = f2bf(bf2f(u.x) * scale);
      uq.y = f2bf(bf2f(u.y) * scale);
      uq.z = f2bf(bf2f(u.z) * scale);
      uq.w = f2bf(bf2f(u.w) * scale);
      *reinterpret_cast<ushort4*>(&qs[h * 2560 + n * 40 + d]) = uq;
    } else if (sect == 1){
      *reinterpret_cast<ushort4*>(&ks[h * 2560 + n * 40 + d]) = u;
    } else {
      vt[h * 2304 + (d + 0) * 72 + n] = u.x;
      vt[h * 2304 + (d + 1) * 72 + n] = u.y;
      vt[h * 2304 + (d + 2) * 72 + n] = u.z;
      vt[h * 2304 + (d + 3) * 72 + n] = u.w;
    }
  }
  for (int idx = tid; idx < 1440; idx += 256){
    int h = idx / 480, rem = idx - h * 480;
    int r = rem >> 5, k = rem & 31;
    qs[h * 2560 + (49 + r) * 40 + k] = 0;
    ks[h * 2560 + (49 + r) * 40 + k] = 0;
  }
  for (int idx = tid; idx < 1440; idx += 256){
    int h = idx / 480, rem = idx - h * 480;
    int d = rem / 15, kk = rem - d * 15;
    vt[h * 2304 + d * 72 + 49 + kk] = 0;
  }
  __syncthreads();

  int wave = tid >> 6, lane = tid & 63;
  int ln = lane & 15, qd = lane >> 4;
  int h = wave;

  bfrag8 qf[4];
  if (wave < 3){
    #pragma unroll
    for (int mt = 0; mt < 4; mt++)
      qf[mt] = *reinterpret_cast<const bfrag8*>(&qs[h * 2560 + (mt * 16 + ln) * 40 + qd * 8]);
  }
  __syncthreads();

  f32x4 sf[4][4];
  if (wave < 3){
    const float* cbh = cb + ((size_t)(win & 255) * 3 + h) * 2401;
    #pragma unroll
    for (int nt = 0; nt < 4; nt++){
      bfrag8 kf = *reinterpret_cast<const bfrag8*>(&ks[h * 2560 + (nt * 16 + ln) * 40 + qd * 8]);
      #pragma unroll
      for (int mt = 0; mt < 4; mt++){
        f32x4 z = {0.f, 0.f, 0.f, 0.f};
        sf[mt][nt] = __builtin_amdgcn_mfma_f32_16x16x32_bf16(qf[mt], kf, z, 0, 0, 0);
      }
    }
    #pragma unroll
    for (int mt = 0; mt < 4; mt++)
      #pragma unroll
      for (int nt = 0; nt < 4; nt++)
        #pragma unroll
        for (int r = 0; r < 4; r++){
          int m = mt * 16 + qd * 4 + r, n = nt * 16 + ln;
          if (m < 49 && n < 49) sf[mt][nt][r] += cbh[m * 49 + n];
        }
    #pragma unroll
    for (int mt = 0; mt < 4; mt++){
      float mx[4], sm[4];
      #pragma unroll
      for (int r = 0; r < 4; r++){
        float v = fmaxf(fmaxf(sf[mt][0][r], sf[mt][1][r]), sf[mt][2][r]);
        if (ln == 0) v = fmaxf(v, sf[mt][3][r]);
        mx[r] = v;
      }
      #pragma unroll
      for (int r = 0; r < 4; r++)
        #pragma unroll
        for (int off = 1; off < 16; off <<= 1)
          mx[r] = fmaxf(mx[r], __shfl_xor(mx[r], off));
      #pragma unroll
      for (int r = 0; r < 4; r++){
        float e0 = __expf(sf[mt][0][r] - mx[r]);
        float e1 = __expf(sf[mt][1][r] - mx[r]);
        float e2 = __expf(sf[mt][2][r] - mx[r]);
        float e3 = (ln == 0) ? __expf(sf[mt][3][r] - mx[r]) : 0.f;
        sf[mt][0][r] = e0; sf[mt][1][r] = e1; sf[mt][2][r] = e2; sf[mt][3][r] = e3;
        sm[r] = e0 + e1 + e2 + e3;
      }
      #pragma unroll
      for (int r = 0; r < 4; r++)
        #pragma unroll
        for (int off = 1; off < 16; off <<= 1)
          sm[r] += __shfl_xor(sm[r], off);
      #pragma unroll
      for (int r = 0; r < 4; r++){
        float inv = 1.f / sm[r];
        int m = mt * 16 + qd * 4 + r;
        #pragma unroll
        for (int nt = 0; nt < 4; nt++)
          Ps[h * 4608 + m * 72 + nt * 16 + ln] = f2bf(sf[mt][nt][r] * inv);
      }
    }
  }
  __syncthreads();

  if (wave < 3){
    f32x4 of[4][2];
    #pragma unroll
    for (int mt = 0; mt < 4; mt++)
      #pragma unroll
      for (int dt = 0; dt < 2; dt++) of[mt][dt] = (f32x4){0.f, 0.f, 0.f, 0.f};
    #pragma unroll
    for (int ks2 = 0; ks2 < 2; ks2++){
      bfrag8 vf[2];
      #pragma unroll
      for (int dt = 0; dt < 2; dt++)
        vf[dt] = *reinterpret_cast<const bfrag8*>(
            &vt[h * 2304 + (dt * 16 + ln) * 72 + ks2 * 32 + qd * 8]);
      #pragma unroll
      for (int mt = 0; mt < 4; mt++){
        bfrag8 pf = *reinterpret_cast<const bfrag8*>(
            &Ps[h * 4608 + (mt * 16 + ln) * 72 + ks2 * 32 + qd * 8]);
        #pragma unroll
        for (int dt = 0; dt < 2; dt++)
          of[mt][dt] = __builtin_amdgcn_mfma_f32_16x16x32_bf16(pf, vf[dt], of[mt][dt], 0, 0, 0);
      }
    }
    #pragma unroll
    for (int mt = 0; mt < 4; mt++)
      #pragma unroll
      for (int r = 0; r < 4; r++){
        int m = mt * 16 + qd * 4 + r;
        if (m < 49){
          #pragma unroll
          for (int dt = 0; dt < 2; dt++)
            qkv[base + (size_t)m * 288 + h * 32 + dt * 16 + ln] = f2bf(of[mt][dt][r]);
        }
      }
  }
}

// ---- proj GEMM (MFMA): 128-row blocks, 2 M-tiles/wave -----------------------
__global__ __launch_bounds__(256, 4) void proj_mfma_kernel(
    const unsigned short* __restrict__ qkv, const unsigned short* __restrict__ w,
    const float* __restrict__ bias, const float* __restrict__ xres,
    unsigned short* __restrict__ x2)
{
  __shared__ unsigned short As[128 * 104];
  int tid = threadIdx.x;
  int row0 = blockIdx.x * 128;
  #pragma unroll
  for (int t = 0; t < 6; t++){
    int idx = t * 256 + tid;
    int r = idx / 12, c8 = (idx - r * 12) * 8;
    *reinterpret_cast<bfrag8*>(&As[r * 104 + c8]) =
        *reinterpret_cast<const bfrag8*>(qkv + (size_t)(row0 + r) * 288 + c8);
  }
  __syncthreads();
  int wave = tid >> 6, lane = tid & 63;
  int ln = lane & 15, qd = lane >> 4;
  int mrow = wave * 32;
  bfrag8 af[2][3];
  #pragma unroll
  for (int mt = 0; mt < 2; mt++)
    #pragma unroll
    for (int ks = 0; ks < 3; ks++)
      af[mt][ks] = *reinterpret_cast<const bfrag8*>(
          &As[(mrow + mt * 16 + ln) * 104 + ks * 32 + qd * 8]);
  f32x4 acc[2][6];
  #pragma unroll
  for (int mt = 0; mt < 2; mt++)
    #pragma unroll
    for (int nt = 0; nt < 6; nt++) acc[mt][nt] = (f32x4){0.f,0.f,0.f,0.f};
  #pragma unroll
  for (int nt = 0; nt < 6; nt++){
    const unsigned short* wp = w + (size_t)(nt * 16 + ln) * 96 + qd * 8;
    bfrag8 B0 = *reinterpret_cast<const bfrag8*>(wp);
    bfrag8 B1 = *reinterpret_cast<const bfrag8*>(wp + 32);
    bfrag8 B2 = *reinterpret_cast<const bfrag8*>(wp + 64);
    acc[0][nt] = __builtin_amdgcn_mfma_f32_16x16x32_bf16(af[0][0], B0, acc[0][nt], 0, 0, 0);
    acc[1][nt] = __builtin_amdgcn_mfma_f32_16x16x32_bf16(af[1][0], B0, acc[1][nt], 0, 0, 0);
    acc[0][nt] = __builtin_amdgcn_mfma_f32_16x16x32_bf16(af[0][1], B1, acc[0][nt], 0, 0, 0);
    acc[1][nt] = __builtin_amdgcn_mfma_f32_16x16x32_bf16(af[1][1], B1, acc[1][nt], 0, 0, 0);
    acc[0][nt] = __builtin_amdgcn_mfma_f32_16x16x32_bf16(af[0][2], B2, acc[0][nt], 0, 0, 0);
    acc[1][nt] = __builtin_amdgcn_mfma_f32_16x16x32_bf16(af[1][2], B2, acc[1][nt], 0, 0, 0);
  }
  #pragma unroll
  for (int mt = 0; mt < 2; mt++)
    #pragma unroll
    for (int r = 0; r < 4; r++){
      int gi = win_to_img(row0 + mrow + mt * 16 + qd * 4 + r);
      #pragma unroll
      for (int nt = 0; nt < 6; nt++){
        int col = nt * 16 + ln;
        x2[(size_t)gi * 96 + col] =
            f2bf(acc[mt][nt][r] + bias[col] + xres[(size_t)gi * 96 + col]);
      }
    }
}

// ---- MFMA MLP: 128-row blocks, 2 M-tiles/wave, 96-wide hidden chunks --------
// Hs = 128x104 bf16 (26.6KB), As overlaid. After LN2 barrier all LDS traffic
// is wave-private (own 32 rows) -> no barriers in the chunk loop.
__global__ __launch_bounds__(256, 4) void mlp_mfma_kernel(
    const unsigned short* __restrict__ x2,
    const float* __restrict__ g, const float* __restrict__ b,
    const unsigned short* __restrict__ w1, const float* __restrict__ b1,
    const unsigned short* __restrict__ w2, const float* __restrict__ b2,
    float* __restrict__ out)
{
  __shared__ unsigned short Hs[128 * 104];
  unsigned short* As = Hs;
  int tid = threadIdx.x;
  int row0 = blockIdx.x * 128;

  #pragma unroll
  for (int t = 0; t < 6; t++){
    int idx = t * 256 + tid;
    int r = idx / 12, c8 = (idx - r * 12) * 8;
    *reinterpret_cast<bfrag8*>(&As[r * 104 + c8]) =
        *reinterpret_cast<const bfrag8*>(x2 + (size_t)(row0 + r) * 96 + c8);
  }
  __syncthreads();
  {
    int rr = tid >> 1, part = tid & 1;
    float v[48];
    float s = 0.f, q = 0.f;
    #pragma unroll
    for (int c = 0; c < 48; c++){
      v[c] = bf2f(As[rr * 104 + part * 48 + c]);
      s += v[c]; q += v[c] * v[c];
    }
    s += __shfl_xor(s, 1); q += __shfl_xor(q, 1);
    float mean = s * (1.f / 96.f);
    float rs = rsqrtf(q * (1.f / 96.f) - mean * mean + 1e-5f);
    #pragma unroll
    for (int c = 0; c < 48; c++){
      int cc = part * 48 + c;
      As[rr * 104 + cc] = f2bf((v[c] - mean) * rs * g[cc] + b[cc]);
    }
  }
  __syncthreads();

  int wave = tid >> 6, lane = tid & 63;
  int ln = lane & 15, qd = lane >> 4;
  int mrow = wave * 32;

  bfrag8 afrag[2][3];
  #pragma unroll
  for (int mt = 0; mt < 2; mt++)
    #pragma unroll
    for (int ks = 0; ks < 3; ks++)
      afrag[mt][ks] = *reinterpret_cast<const bfrag8*>(
          &As[(mrow + mt * 16 + ln) * 104 + ks * 32 + qd * 8]);
  // no barrier: As reads & Hs writes below touch only this wave's 32 rows

  f32x4 acc2[2][6];
  #pragma unroll
  for (int mt = 0; mt < 2; mt++)
    #pragma unroll
    for (int nt = 0; nt < 6; nt++) acc2[mt][nt] = (f32x4){0.f,0.f,0.f,0.f};

  for (int chunk = 0; chunk < 4; chunk++){
    // fc1: 96 hidden cols -> Hs (wave-private rows)
    for (int ntl = 0; ntl < 6; ntl++){
      int colg = chunk * 96 + ntl * 16 + ln;
      const unsigned short* wp = w1 + (size_t)colg * 96 + qd * 8;
      bfrag8 B0 = *reinterpret_cast<const bfrag8*>(wp);
      bfrag8 B1 = *reinterpret_cast<const bfrag8*>(wp + 32);
      bfrag8 B2 = *reinterpret_cast<const bfrag8*>(wp + 64);
      f32x4 a0 = {0.f,0.f,0.f,0.f}, a1 = {0.f,0.f,0.f,0.f};
      a0 = __builtin_amdgcn_mfma_f32_16x16x32_bf16(afrag[0][0], B0, a0, 0, 0, 0);
      a1 = __builtin_amdgcn_mfma_f32_16x16x32_bf16(afrag[1][0], B0, a1, 0, 0, 0);
      a0 = __builtin_amdgcn_mfma_f32_16x16x32_bf16(afrag[0][1], B1, a0, 0, 0, 0);
      a1 = __builtin_amdgcn_mfma_f32_16x16x32_bf16(afrag[1][1], B1, a1, 0, 0, 0);
      a0 = __builtin_amdgcn_mfma_f32_16x16x32_bf16(afrag[0][2], B2, a0, 0, 0, 0);
      a1 = __builtin_amdgcn_mfma_f32_16x16x32_bf16(afrag[1][2], B2, a1, 0, 0, 0);
      float bias = b1[colg];
      #pragma unroll
      for (int r = 0; r < 4; r++){
        float v0 = a0[r] + bias;
        float v1 = a1[r] + bias;
        float g0 = 0.5f * v0 * (1.f + erff(v0 * 0.70710678118f));
        float g1 = 0.5f * v1 * (1.f + erff(v1 * 0.70710678118f));
        Hs[(mrow + qd * 4 + r) * 104 + ntl * 16 + ln] = f2bf(g0);
        Hs[(mrow + 16 + qd * 4 + r) * 104 + ntl * 16 + ln] = f2bf(g1);
      }
    }
    // fc2: this chunk's K-slice (wave-private Hs rows; no barrier)
    #pragma unroll
    for (int ks2 = 0; ks2 < 3; ks2++){
      bfrag8 p0 = *reinterpret_cast<const bfrag8*>(&Hs[(mrow + ln) * 104 + ks2 * 32 + qd * 8]);
      bfrag8 p1 = *reinterpret_cast<const bfrag8*>(&Hs[(mrow + 16 + ln) * 104 + ks2 * 32 + qd * 8]);
      #pragma unroll
      for (int nt = 0; nt < 6; nt++){
        bfrag8 B = *reinterpret_cast<const bfrag8*>(
            w2 + (size_t)(nt * 16 + ln) * 384 + chunk * 96 + ks2 * 32 + qd * 8);
        acc2[0][nt] = __builtin_amdgcn_mfma_f32_16x16x32_bf16(p0, B, acc2[0][nt], 0, 0, 0);
        acc2[1][nt] = __builtin_amdgcn_mfma_f32_16x16x32_bf16(p1, B, acc2[1][nt], 0, 0, 0);
      }
    }
  }

  #pragma unroll
  for (int nt = 0; nt < 6; nt++){
    int col = nt * 16 + ln;
    float bias = b2[col];
    #pragma unroll
    for (int mt = 0; mt < 2; mt++)
      #pragma unroll
      for (int r = 0; r < 4; r++){
        int grow = row0 + mrow + mt * 16 + qd * 4 + r;
        out[(size_t)grow * 96 + col] = acc2[mt][nt][r] + bias + bf2f(x2[(size_t)grow * 96 + col]);
      }
  }
}

extern "C" void kernel_launch(void* const* d_in, const int* in_sizes, int n_in,
                              void* d_out, int out_size, void* d_ws, size_t ws_size,
                              hipStream_t stream)
{
  const float* x      = (const float*)d_in[0];
  const float* mask   = (const float*)d_in[1];
  const float* n1g    = (const float*)d_in[2];
  const float* n1b    = (const float*)d_in[3];
  const float* qkv_w  = (const float*)d_in[4];
  const float* qkv_b  = (const float*)d_in[5];
  const float* relt   = (const float*)d_in[6];
  const float* proj_w = (const float*)d_in[7];
  const float* proj_b = (const float*)d_in[8];
  const float* n2g    = (const float*)d_in[9];
  const float* n2b    = (const float*)d_in[10];
  const float* fc1_w  = (const float*)d_in[11];
  const float* fc1_b  = (const float*)d_in[12];
  const float* fc2_w  = (const float*)d_in[13];
  const float* fc2_b  = (const float*)d_in[14];
  float* outp = (float*)d_out;
  (void)in_sizes; (void)n_in; (void)out_size; (void)ws_size;

  const size_t M = 200704;
  char* ws = (char*)d_ws;
  unsigned short* qkvb   = (unsigned short*)ws;                          // 115.6 MB
  size_t o = M * 288 * 2;
  unsigned short* x2     = (unsigned short*)(ws + o); o += M * 96 * 2;   // 38.5 MB
  float*          meanb  = (float*)(ws + o); o += M * 4;
  float*          rstdb  = (float*)(ws + o); o += M * 4;
  unsigned short* w1bf   = (unsigned short*)(ws + o); o += 384 * 96 * 2;
  unsigned short* w2bf   = (unsigned short*)(ws + o); o += 96 * 384 * 2;
  unsigned short* wqkvbf = (unsigned short*)(ws + o); o += 288 * 96 * 2;
  unsigned short* wprojbf= (unsigned short*)(ws + o); o += 96 * 96 * 2;
  float*          cbuf   = (float*)(ws + o); o += 256 * 3 * 2401 * 4;    // 7.4 MB

  cvt_kernel<<<144, 256, 0, stream>>>(fc1_w, w1bf, 384 * 96);
  cvt_kernel<<<144, 256, 0, stream>>>(fc2_w, w2bf, 96 * 384);
  cvt_kernel<<<108, 256, 0, stream>>>(qkv_w, wqkvbf, 288 * 96);
  cvt_kernel<<<36, 256, 0, stream>>>(proj_w, wprojbf, 96 * 96);
  cb_kernel<<<7203, 256, 0, stream>>>(relt, mask, cbuf);
  ln_stats_kernel<<<50176, 256, 0, stream>>>(x, meanb, rstdb);
  qkv_mfma_kernel<<<1568, 256, 0, stream>>>(
      x, meanb, rstdb, n1g, n1b, wqkvbf, qkv_b, qkvb);
  attn_mfma_kernel<<<4096, 256, 0, stream>>>(qkvb, cbuf);
  proj_mfma_kernel<<<1568, 256, 0, stream>>>(qkvb, wprojbf, proj_b, x, x2);
  mlp_mfma_kernel<<<1568, 256, 0, stream>>>(
      x2, n2g, n2b, w1bf, fc1_b, w2bf, fc2_b, outp);
}

// Round 7
// 404.146 us; speedup vs baseline: 6.7282x; 1.2566x over previous
//
#include <hip/hip_runtime.h>
#include <hip/hip_bf16.h>
#include <math.h>

// Swin block, MI355X round 6: fused per-window kernel (LN1 + qkv GEMM + attn
// + proj + scatter/residual, all in LDS) + fast-GELU MLP. Eliminates the qkvb
// intermediate (~270MB HBM) and ln_stats. M=200704, C=96, heads=3, hd=32.

typedef __attribute__((ext_vector_type(8))) short bfrag8;   // 8 bf16 = 4 VGPRs
typedef __attribute__((ext_vector_type(4))) float f32x4;

__device__ __forceinline__ float bf2f(unsigned short u){
  union { unsigned int i; float f; } c; c.i = ((unsigned int)u) << 16; return c.f;
}
__device__ __forceinline__ unsigned short f2bf(float f){
  __hip_bfloat16 h = __float2bfloat16(f);
  union { __hip_bfloat16 h; unsigned short u; } c; c.h = h; return c.u;
}
// tanh-form GELU via sigmoid: x * sigmoid(1.5957691(x + 0.044715 x^3))
__device__ __forceinline__ float gelu_f(float x){
  float x2 = x * x;
  float z  = x + 0.044715f * x * x2;
  float u  = __expf(-1.5957691f * z);
  return x / (1.f + u);
}

// window-order row r (win*49+n) -> image row (b*12544 + h*112 + w), shift +3.
__device__ __forceinline__ int win_to_img(int r){
  int win = r / 49, n = r - win * 49;
  int b  = win >> 8, wi = win & 255;
  int wh = wi >> 4,  ww = wi & 15;
  int i  = n / 7,    j  = n - i * 7;
  int hs = wh * 7 + i + 3; if (hs >= 112) hs -= 112;
  int ws = ww * 7 + j + 3; if (ws >= 112) ws -= 112;
  return b * 12544 + hs * 112 + ws;
}

// ---- all 4 weight conversions in one kernel ---------------------------------
__global__ __launch_bounds__(256) void cvt_all_kernel(
    const float* __restrict__ s1, unsigned short* __restrict__ d1,   // 36864
    const float* __restrict__ s2, unsigned short* __restrict__ d2,   // 36864
    const float* __restrict__ s3, unsigned short* __restrict__ d3,   // 27648
    const float* __restrict__ s4, unsigned short* __restrict__ d4)   // 9216
{
  int i = blockIdx.x * 256 + threadIdx.x;
  if      (i < 36864)  d1[i]          = f2bf(s1[i]);
  else if (i < 73728)  d2[i - 36864]  = f2bf(s2[i - 36864]);
  else if (i < 101376) d3[i - 73728]  = f2bf(s3[i - 73728]);
  else if (i < 110592) d4[i - 101376] = f2bf(s4[i - 101376]);
}

// ---- combined rel-bias + shift-mask table: cb[w][h][m][n] fp32 --------------
__global__ __launch_bounds__(256) void cb_kernel(
    const float* __restrict__ relt, const float* __restrict__ mask,
    float* __restrict__ cb)
{
  int idx = blockIdx.x * 256 + threadIdx.x;
  if (idx >= 256 * 3 * 2401) return;
  int w = idx / 7203, rem = idx - w * 7203;
  int h = rem / 2401, mn = rem - h * 2401;
  int m = mn / 49, n = mn - m * 49;
  int i1 = m / 7, j1 = m - i1 * 7;
  int i2 = n / 7, j2 = n - i2 * 7;
  int ridx = (i1 - i2 + 6) * 13 + (j1 - j2 + 6);
  cb[idx] = relt[ridx * 3 + h] + mask[w * 2401 + mn];
}

// ---- fused per-window kernel: LN1 + qkv + attention + proj ------------------
// LDS 72.2KB: UA = As(64x104, first 13.3KB) / Ps(3x64x72) union;
//             UK = ks(3x64x40) / Os(64x104) union; qs, vt separate.
__global__ __launch_bounds__(256) void fused_win_kernel(
    const float* __restrict__ x,
    const float* __restrict__ g1, const float* __restrict__ b1n,
    const unsigned short* __restrict__ wqkv, const float* __restrict__ bqkv,
    const float* __restrict__ cb,
    const unsigned short* __restrict__ wproj, const float* __restrict__ bproj,
    unsigned short* __restrict__ x2)
{
  __shared__ unsigned short UA[13824];        // As (first 6656 ushorts) / Ps
  __shared__ unsigned short qs[3 * 64 * 40];  // 7680
  __shared__ unsigned short UK[3 * 64 * 40];  // ks / Os (64*104=6656)
  __shared__ unsigned short vt[3 * 32 * 72];  // 6912
  unsigned short* As = UA;
  unsigned short* Ps = UA;
  unsigned short* ksm = UK;
  unsigned short* Os = UK;

  int win = blockIdx.x, tid = threadIdx.x;
  const float scale = 0.17677669529663687f;

  // ---- phase 0: stage + LN1 (4 threads per row; rows 49-63 zeroed) ----------
  {
    int r = tid >> 2, part = tid & 3;
    if (r < 49){
      int gr = win_to_img(win * 49 + r);
      const float* rowp = x + (size_t)gr * 96 + part * 24;
      float v[24]; float s = 0.f, q = 0.f;
      #pragma unroll
      for (int c = 0; c < 24; c++){ v[c] = rowp[c]; s += v[c]; q += v[c] * v[c]; }
      s += __shfl_xor(s, 1); q += __shfl_xor(q, 1);
      s += __shfl_xor(s, 2); q += __shfl_xor(q, 2);
      float mean = s * (1.f / 96.f);
      float rs = rsqrtf(q * (1.f / 96.f) - mean * mean + 1e-5f);
      #pragma unroll
      for (int c = 0; c < 24; c++){
        int cc = part * 24 + c;
        As[r * 104 + cc] = f2bf((v[c] - mean) * rs * g1[cc] + b1n[cc]);
      }
    } else {
      #pragma unroll
      for (int c = 0; c < 24; c++) As[r * 104 + part * 24 + c] = 0;
    }
  }
  __syncthreads();

  int wave = tid >> 6, lane = tid & 63;
  int ln = lane & 15, qd = lane >> 4;
  int mrow = wave * 16;

  // ---- phase 1: qkv GEMM -> qs / ks / vt ------------------------------------
  {
    bfrag8 af[3];
    #pragma unroll
    for (int k3 = 0; k3 < 3; k3++)
      af[k3] = *reinterpret_cast<const bfrag8*>(&As[(mrow + ln) * 104 + k3 * 32 + qd * 8]);
    for (int nt = 0; nt < 18; nt++){
      int col = nt * 16 + ln;
      const unsigned short* wp = wqkv + (size_t)col * 96 + qd * 8;
      bfrag8 B0 = *reinterpret_cast<const bfrag8*>(wp);
      bfrag8 B1 = *reinterpret_cast<const bfrag8*>(wp + 32);
      bfrag8 B2 = *reinterpret_cast<const bfrag8*>(wp + 64);
      f32x4 acc = {0.f, 0.f, 0.f, 0.f};
      acc = __builtin_amdgcn_mfma_f32_16x16x32_bf16(af[0], B0, acc, 0, 0, 0);
      acc = __builtin_amdgcn_mfma_f32_16x16x32_bf16(af[1], B1, acc, 0, 0, 0);
      acc = __builtin_amdgcn_mfma_f32_16x16x32_bf16(af[2], B2, acc, 0, 0, 0);
      float bs = bqkv[col];
      if (nt < 6){
        int h = col >> 5, d = col & 31;
        #pragma unroll
        for (int r = 0; r < 4; r++){
          int m = mrow + qd * 4 + r;
          qs[h * 2560 + m * 40 + d] = f2bf((acc[r] + bs) * scale);
        }
      } else if (nt < 12){
        int cc = col - 96; int h = cc >> 5, d = cc & 31;
        #pragma unroll
        for (int r = 0; r < 4; r++){
          int m = mrow + qd * 4 + r;
          ksm[h * 2560 + m * 40 + d] = f2bf(acc[r] + bs);
        }
      } else {
        int cc = col - 192; int h = cc >> 5, d = cc & 31;
        #pragma unroll
        for (int r = 0; r < 4; r++){
          int m = mrow + qd * 4 + r;
          vt[h * 2304 + d * 72 + m] = f2bf(acc[r] + bs);
        }
      }
    }
  }
  __syncthreads();

  // ---- phase 2: QK^T + bias/mask + softmax -> Ps (overlays As) --------------
  int h = wave;
  if (wave < 3){
    bfrag8 qf[4];
    #pragma unroll
    for (int mt = 0; mt < 4; mt++)
      qf[mt] = *reinterpret_cast<const bfrag8*>(&qs[h * 2560 + (mt * 16 + ln) * 40 + qd * 8]);
    f32x4 sf[4][4];
    const float* cbh = cb + ((size_t)(win & 255) * 3 + h) * 2401;
    #pragma unroll
    for (int nt = 0; nt < 4; nt++){
      bfrag8 kf = *reinterpret_cast<const bfrag8*>(&ksm[h * 2560 + (nt * 16 + ln) * 40 + qd * 8]);
      #pragma unroll
      for (int mt = 0; mt < 4; mt++){
        f32x4 z = {0.f, 0.f, 0.f, 0.f};
        sf[mt][nt] = __builtin_amdgcn_mfma_f32_16x16x32_bf16(qf[mt], kf, z, 0, 0, 0);
      }
    }
    #pragma unroll
    for (int mt = 0; mt < 4; mt++)
      #pragma unroll
      for (int nt = 0; nt < 4; nt++)
        #pragma unroll
        for (int r = 0; r < 4; r++){
          int m = mt * 16 + qd * 4 + r, n = nt * 16 + ln;
          if (m < 49 && n < 49) sf[mt][nt][r] += cbh[m * 49 + n];
        }
    #pragma unroll
    for (int mt = 0; mt < 4; mt++){
      float mx[4], sm[4];
      #pragma unroll
      for (int r = 0; r < 4; r++){
        float v = fmaxf(fmaxf(sf[mt][0][r], sf[mt][1][r]), sf[mt][2][r]);
        if (ln == 0) v = fmaxf(v, sf[mt][3][r]);
        mx[r] = v;
      }
      #pragma unroll
      for (int r = 0; r < 4; r++)
        #pragma unroll
        for (int off = 1; off < 16; off <<= 1)
          mx[r] = fmaxf(mx[r], __shfl_xor(mx[r], off));
      #pragma unroll
      for (int r = 0; r < 4; r++){
        float e0 = __expf(sf[mt][0][r] - mx[r]);
        float e1 = __expf(sf[mt][1][r] - mx[r]);
        float e2 = __expf(sf[mt][2][r] - mx[r]);
        float e3 = (ln == 0) ? __expf(sf[mt][3][r] - mx[r]) : 0.f;
        sf[mt][0][r] = e0; sf[mt][1][r] = e1; sf[mt][2][r] = e2; sf[mt][3][r] = e3;
        sm[r] = e0 + e1 + e2 + e3;
      }
      #pragma unroll
      for (int r = 0; r < 4; r++)
        #pragma unroll
        for (int off = 1; off < 16; off <<= 1)
          sm[r] += __shfl_xor(sm[r], off);
      #pragma unroll
      for (int r = 0; r < 4; r++){
        float inv = 1.f / sm[r];
        int m = mt * 16 + qd * 4 + r;
        #pragma unroll
        for (int nt = 0; nt < 4; nt++)
          Ps[h * 4608 + m * 72 + nt * 16 + ln] = f2bf(sf[mt][nt][r] * inv);
      }
    }
  }
  __syncthreads();   // all kf reads done -> Os may overwrite ks region

  // ---- phase 3: PV -> Os (overlays ks) --------------------------------------
  if (wave < 3){
    f32x4 of[4][2];
    #pragma unroll
    for (int mt = 0; mt < 4; mt++)
      #pragma unroll
      for (int dt = 0; dt < 2; dt++) of[mt][dt] = (f32x4){0.f, 0.f, 0.f, 0.f};
    #pragma unroll
    for (int k2 = 0; k2 < 2; k2++){
      bfrag8 vf[2];
      #pragma unroll
      for (int dt = 0; dt < 2; dt++)
        vf[dt] = *reinterpret_cast<const bfrag8*>(
            &vt[h * 2304 + (dt * 16 + ln) * 72 + k2 * 32 + qd * 8]);
      #pragma unroll
      for (int mt = 0; mt < 4; mt++){
        bfrag8 pf = *reinterpret_cast<const bfrag8*>(
            &Ps[h * 4608 + (mt * 16 + ln) * 72 + k2 * 32 + qd * 8]);
        #pragma unroll
        for (int dt = 0; dt < 2; dt++)
          of[mt][dt] = __builtin_amdgcn_mfma_f32_16x16x32_bf16(pf, vf[dt], of[mt][dt], 0, 0, 0);
      }
    }
    #pragma unroll
    for (int mt = 0; mt < 4; mt++)
      #pragma unroll
      for (int r = 0; r < 4; r++){
        int m = mt * 16 + qd * 4 + r;
        #pragma unroll
        for (int dt = 0; dt < 2; dt++)
          Os[m * 104 + h * 32 + dt * 16 + ln] = f2bf(of[mt][dt][r]);
      }
  }
  __syncthreads();

  // ---- phase 4: proj GEMM + reverse-shift scatter + residual -> x2 ----------
  {
    bfrag8 ap[3];
    #pragma unroll
    for (int k3 = 0; k3 < 3; k3++)
      ap[k3] = *reinterpret_cast<const bfrag8*>(&Os[(mrow + ln) * 104 + k3 * 32 + qd * 8]);
    f32x4 pacc[6];
    #pragma unroll
    for (int nt = 0; nt < 6; nt++){
      const unsigned short* wp = wproj + (size_t)(nt * 16 + ln) * 96 + qd * 8;
      bfrag8 B0 = *reinterpret_cast<const bfrag8*>(wp);
      bfrag8 B1 = *reinterpret_cast<const bfrag8*>(wp + 32);
      bfrag8 B2 = *reinterpret_cast<const bfrag8*>(wp + 64);
      f32x4 acc = {0.f, 0.f, 0.f, 0.f};
      acc = __builtin_amdgcn_mfma_f32_16x16x32_bf16(ap[0], B0, acc, 0, 0, 0);
      acc = __builtin_amdgcn_mfma_f32_16x16x32_bf16(ap[1], B1, acc, 0, 0, 0);
      acc = __builtin_amdgcn_mfma_f32_16x16x32_bf16(ap[2], B2, acc, 0, 0, 0);
      pacc[nt] = acc;
    }
    #pragma unroll
    for (int r = 0; r < 4; r++){
      int m = mrow + qd * 4 + r;
      if (m < 49){
        int gi = win_to_img(win * 49 + m);
        #pragma unroll
        for (int nt = 0; nt < 6; nt++){
          int col = nt * 16 + ln;
          x2[(size_t)gi * 96 + col] =
              f2bf(pacc[nt][r] + bproj[col] + x[(size_t)gi * 96 + col]);
        }
      }
    }
  }
}

// ---- MFMA MLP: 128-row blocks, 2 M-tiles/wave, fast GELU --------------------
__global__ __launch_bounds__(256, 4) void mlp_mfma_kernel(
    const unsigned short* __restrict__ x2,
    const float* __restrict__ g, const float* __restrict__ b,
    const unsigned short* __restrict__ w1, const float* __restrict__ b1,
    const unsigned short* __restrict__ w2, const float* __restrict__ b2,
    float* __restrict__ out)
{
  __shared__ unsigned short Hs[128 * 104];
  unsigned short* As = Hs;
  int tid = threadIdx.x;
  int row0 = blockIdx.x * 128;

  #pragma unroll
  for (int t = 0; t < 6; t++){
    int idx = t * 256 + tid;
    int r = idx / 12, c8 = (idx - r * 12) * 8;
    *reinterpret_cast<bfrag8*>(&As[r * 104 + c8]) =
        *reinterpret_cast<const bfrag8*>(x2 + (size_t)(row0 + r) * 96 + c8);
  }
  __syncthreads();
  {
    int rr = tid >> 1, part = tid & 1;
    float v[48];
    float s = 0.f, q = 0.f;
    #pragma unroll
    for (int c = 0; c < 48; c++){
      v[c] = bf2f(As[rr * 104 + part * 48 + c]);
      s += v[c]; q += v[c] * v[c];
    }
    s += __shfl_xor(s, 1); q += __shfl_xor(q, 1);
    float mean = s * (1.f / 96.f);
    float rs = rsqrtf(q * (1.f / 96.f) - mean * mean + 1e-5f);
    #pragma unroll
    for (int c = 0; c < 48; c++){
      int cc = part * 48 + c;
      As[rr * 104 + cc] = f2bf((v[c] - mean) * rs * g[cc] + b[cc]);
    }
  }
  __syncthreads();

  int wave = tid >> 6, lane = tid & 63;
  int ln = lane & 15, qd = lane >> 4;
  int mrow = wave * 32;

  bfrag8 afrag[2][3];
  #pragma unroll
  for (int mt = 0; mt < 2; mt++)
    #pragma unroll
    for (int k3 = 0; k3 < 3; k3++)
      afrag[mt][k3] = *reinterpret_cast<const bfrag8*>(
          &As[(mrow + mt * 16 + ln) * 104 + k3 * 32 + qd * 8]);
  // no barrier: As reads & Hs writes below touch only this wave's 32 rows

  f32x4 acc2[2][6];
  #pragma unroll
  for (int mt = 0; mt < 2; mt++)
    #pragma unroll
    for (int nt = 0; nt < 6; nt++) acc2[mt][nt] = (f32x4){0.f,0.f,0.f,0.f};

  for (int chunk = 0; chunk < 4; chunk++){
    #pragma unroll 2
    for (int ntl = 0; ntl < 6; ntl++){
      int colg = chunk * 96 + ntl * 16 + ln;
      const unsigned short* wp = w1 + (size_t)colg * 96 + qd * 8;
      bfrag8 B0 = *reinterpret_cast<const bfrag8*>(wp);
      bfrag8 B1 = *reinterpret_cast<const bfrag8*>(wp + 32);
      bfrag8 B2 = *reinterpret_cast<const bfrag8*>(wp + 64);
      f32x4 a0 = {0.f,0.f,0.f,0.f}, a1 = {0.f,0.f,0.f,0.f};
      a0 = __builtin_amdgcn_mfma_f32_16x16x32_bf16(afrag[0][0], B0, a0, 0, 0, 0);
      a1 = __builtin_amdgcn_mfma_f32_16x16x32_bf16(afrag[1][0], B0, a1, 0, 0, 0);
      a0 = __builtin_amdgcn_mfma_f32_16x16x32_bf16(afrag[0][1], B1, a0, 0, 0, 0);
      a1 = __builtin_amdgcn_mfma_f32_16x16x32_bf16(afrag[1][1], B1, a1, 0, 0, 0);
      a0 = __builtin_amdgcn_mfma_f32_16x16x32_bf16(afrag[0][2], B2, a0, 0, 0, 0);
      a1 = __builtin_amdgcn_mfma_f32_16x16x32_bf16(afrag[1][2], B2, a1, 0, 0, 0);
      float bias = b1[colg];
      #pragma unroll
      for (int r = 0; r < 4; r++){
        Hs[(mrow + qd * 4 + r) * 104 + ntl * 16 + ln] = f2bf(gelu_f(a0[r] + bias));
        Hs[(mrow + 16 + qd * 4 + r) * 104 + ntl * 16 + ln] = f2bf(gelu_f(a1[r] + bias));
      }
    }
    #pragma unroll
    for (int k2 = 0; k2 < 3; k2++){
      bfrag8 p0 = *reinterpret_cast<const bfrag8*>(&Hs[(mrow + ln) * 104 + k2 * 32 + qd * 8]);
      bfrag8 p1 = *reinterpret_cast<const bfrag8*>(&Hs[(mrow + 16 + ln) * 104 + k2 * 32 + qd * 8]);
      #pragma unroll
      for (int nt = 0; nt < 6; nt++){
        bfrag8 B = *reinterpret_cast<const bfrag8*>(
            w2 + (size_t)(nt * 16 + ln) * 384 + chunk * 96 + k2 * 32 + qd * 8);
        acc2[0][nt] = __builtin_amdgcn_mfma_f32_16x16x32_bf16(p0, B, acc2[0][nt], 0, 0, 0);
        acc2[1][nt] = __builtin_amdgcn_mfma_f32_16x16x32_bf16(p1, B, acc2[1][nt], 0, 0, 0);
      }
    }
  }

  #pragma unroll
  for (int nt = 0; nt < 6; nt++){
    int col = nt * 16 + ln;
    float bias = b2[col];
    #pragma unroll
    for (int mt = 0; mt < 2; mt++)
      #pragma unroll
      for (int r = 0; r < 4; r++){
        int grow = row0 + mrow + mt * 16 + qd * 4 + r;
        out[(size_t)grow * 96 + col] = acc2[mt][nt][r] + bias + bf2f(x2[(size_t)grow * 96 + col]);
      }
  }
}

extern "C" void kernel_launch(void* const* d_in, const int* in_sizes, int n_in,
                              void* d_out, int out_size, void* d_ws, size_t ws_size,
                              hipStream_t stream)
{
  const float* x      = (const float*)d_in[0];
  const float* mask   = (const float*)d_in[1];
  const float* n1g    = (const float*)d_in[2];
  const float* n1b    = (const float*)d_in[3];
  const float* qkv_w  = (const float*)d_in[4];
  const float* qkv_b  = (const float*)d_in[5];
  const float* relt   = (const float*)d_in[6];
  const float* proj_w = (const float*)d_in[7];
  const float* proj_b = (const float*)d_in[8];
  const float* n2g    = (const float*)d_in[9];
  const float* n2b    = (const float*)d_in[10];
  const float* fc1_w  = (const float*)d_in[11];
  const float* fc1_b  = (const float*)d_in[12];
  const float* fc2_w  = (const float*)d_in[13];
  const float* fc2_b  = (const float*)d_in[14];
  float* outp = (float*)d_out;
  (void)in_sizes; (void)n_in; (void)out_size; (void)ws_size; (void)mask;

  const size_t M = 200704;
  char* ws = (char*)d_ws;
  unsigned short* x2     = (unsigned short*)ws;              // 38.5 MB
  size_t o = M * 96 * 2;
  unsigned short* w1bf   = (unsigned short*)(ws + o); o += 384 * 96 * 2;
  unsigned short* w2bf   = (unsigned short*)(ws + o); o += 96 * 384 * 2;
  unsigned short* wqkvbf = (unsigned short*)(ws + o); o += 288 * 96 * 2;
  unsigned short* wprojbf= (unsigned short*)(ws + o); o += 96 * 96 * 2;
  float*          cbuf   = (float*)(ws + o); o += (size_t)256 * 3 * 2401 * 4;  // 7.4 MB

  cvt_all_kernel<<<432, 256, 0, stream>>>(
      fc1_w, w1bf, fc2_w, w2bf, qkv_w, wqkvbf, proj_w, wprojbf);
  cb_kernel<<<7203, 256, 0, stream>>>(relt, mask, cbuf);
  fused_win_kernel<<<4096, 256, 0, stream>>>(
      x, n1g, n1b, wqkvbf, qkv_b, cbuf, wprojbf, proj_b, x2);
  mlp_mfma_kernel<<<1568, 256, 0, stream>>>(
      x2, n2g, n2b, w1bf, fc1_b, w2bf, fc2_b, outp);
}